// Round 6
// baseline (351.797 us; speedup 1.0000x reference)
//
#include <hip/hip_runtime.h>

#define NROWS 16384   // B*L
#define LSEQ  2048
#define NB    8

typedef short v8s __attribute__((ext_vector_type(8)));
typedef float v4f __attribute__((ext_vector_type(4)));

__device__ __forceinline__ unsigned short f2bf(float f) {
    unsigned int u = __float_as_uint(f);
    return (unsigned short)((u + 0x7fffu + ((u >> 16) & 1u)) >> 16);
}
__device__ __forceinline__ float bf2f(unsigned short u) {
    return __uint_as_float(((unsigned int)u) << 16);
}

// async global->LDS, 16B per lane; LDS dest is wave-uniform base + lane*16
__device__ __forceinline__ void glds16(const void* g, void* l) {
    __builtin_amdgcn_global_load_lds(
        (__attribute__((address_space(1))) void*)g,
        (__attribute__((address_space(3))) void*)l,
        16, 0, 0);
}

// fast exact-GELU: Abramowitz-Stegun 5-term erf, |err|<1.5e-7
__device__ __forceinline__ float fast_gelu(float v) {
    float z = fabsf(v) * 0.70710678118654752f;
    float t = __builtin_amdgcn_rcpf(1.0f + 0.3275911f * z);
    float poly = t * (0.254829592f + t * (-0.284496736f + t * (1.421413741f +
                 t * (-1.453152027f + t * 1.061405429f))));
    float erfz = 1.0f - poly * __expf(-z * z);
    float er = copysignf(erfz, v);
    return 0.5f * v * (1.0f + er);
}
__device__ __forceinline__ float fast_tanh(float y) {
    float e = __expf(2.0f * y);
    return (e - 1.0f) * __builtin_amdgcn_rcpf(e + 1.0f);
}

// XCD row-swizzle: block b (of 4096, 4 rows each) -> rows of 128-row tile T with
// T%8 == b%8, so the producer's XCD matches the GEMM reader's XCD (= (m>>7)%8).
__device__ __forceinline__ long swizzled_row(int b, int wave) {
    int T = (b & 7) + (((b >> 3) & 15) << 3);   // 0..127, T%8 == b%8
    int chunk = b >> 7;                          // 0..31
    return (long)T * 128 + chunk * 4 + wave;
}

// ------- merged setup: embed (blocks 0..4095, XCD-swizzled) | weight transposes
//         (4096..6239) | class converts (6240..6242); embed also emits LN0(hl) -------
__global__ __launch_bounds__(256) void setup_kernel(
        const int* __restrict__ ids,
        const float* __restrict__ tok, const float* __restrict__ pos,
        const float* __restrict__ g0, const float* __restrict__ b0,
        unsigned short* __restrict__ x, unsigned short* __restrict__ hl,
        const float* __restrict__ w1, const float* __restrict__ w2,
        const float* __restrict__ wa, const float* __restrict__ wb, const float* __restrict__ wc,
        const float* __restrict__ ca, const float* __restrict__ cb, const float* __restrict__ cc,
        unsigned short* __restrict__ w1T, unsigned short* __restrict__ w2T,
        unsigned short* __restrict__ wabcT, unsigned short* __restrict__ clsb) {
    int blk = blockIdx.x;
    int t = threadIdx.x;
    if (blk < 4096) {
        int wave = t >> 6, lane = t & 63;
        long row = swizzled_row(blk, wave);
        int l = (int)(row & (LSEQ - 1));
        int id = ids[row];
        int d = lane * 8;
        float4 t0 = *(const float4*)(tok + (size_t)id * 512 + d);
        float4 t1 = *(const float4*)(tok + (size_t)id * 512 + d + 4);
        float4 p0 = *(const float4*)(pos + (size_t)l * 512 + d);
        float4 p1 = *(const float4*)(pos + (size_t)l * 512 + d + 4);
        float a[8] = {t0.x + p0.x, t0.y + p0.y, t0.z + p0.z, t0.w + p0.w,
                      t1.x + p1.x, t1.y + p1.y, t1.z + p1.z, t1.w + p1.w};
        unsigned int xp[4];
        #pragma unroll
        for (int i = 0; i < 4; ++i)
            xp[i] = (unsigned int)f2bf(a[2 * i]) | ((unsigned int)f2bf(a[2 * i + 1]) << 16);
        *(uint4*)(x + row * 512 + d) = *(uint4*)xp;
        float s = 0.f, s2 = 0.f;
        #pragma unroll
        for (int i = 0; i < 8; ++i) { s += a[i]; s2 += a[i] * a[i]; }
        #pragma unroll
        for (int o = 32; o > 0; o >>= 1) { s += __shfl_down(s, o); s2 += __shfl_down(s2, o); }
        s = __shfl(s, 0); s2 = __shfl(s2, 0);
        float m = s * (1.0f / 512.0f);
        float rinv = 1.0f / sqrtf(s2 * (1.0f / 512.0f) - m * m + 1e-5f);
        float4 ga = *(const float4*)(g0 + d), gb = *(const float4*)(g0 + d + 4);
        float4 ba = *(const float4*)(b0 + d), bb2 = *(const float4*)(b0 + d + 4);
        float gg[8] = {ga.x, ga.y, ga.z, ga.w, gb.x, gb.y, gb.z, gb.w};
        float bb[8] = {ba.x, ba.y, ba.z, ba.w, bb2.x, bb2.y, bb2.z, bb2.w};
        unsigned int hp[4];
        #pragma unroll
        for (int i = 0; i < 4; ++i) {
            unsigned short lo = f2bf((a[2 * i]     - m) * rinv * gg[2 * i]     + bb[2 * i]);
            unsigned short hi = f2bf((a[2 * i + 1] - m) * rinv * gg[2 * i + 1] + bb[2 * i + 1]);
            hp[i] = (unsigned int)lo | ((unsigned int)hi << 16);
        }
        *(uint4*)(hl + row * 512 + d) = *(uint4*)hp;
    } else if (blk < 6240) {
        int id = blk - 4096;
        int tx = t & 31, ty = t >> 5;
        const float* in; unsigned short* out; int R, C, bx, by, ldo;
        if (id < 1024) {
            int l = id >> 9, r = id & 511;
            in = w1 + l * 524288; out = w1T + l * 524288;
            R = 512; C = 1024; bx = r & 31; by = r >> 5; ldo = 512;
        } else if (id < 2048) {
            int l = (id - 1024) >> 9, r = (id - 1024) & 511;
            in = w2 + l * 524288; out = w2T + l * 524288;
            R = 1024; C = 512; bx = r & 15; by = r >> 4; ldo = 1024;
        } else {
            int g = (id - 2048) >> 5, r = (id - 2048) & 31;
            in = (g == 0) ? wa : (g == 1) ? wb : wc;
            out = wabcT + g * 32768;
            R = 512; C = 64; bx = r & 1; by = r >> 1; ldo = 512;
        }
        __shared__ unsigned short tile[32][33];
        int c0 = bx * 32, r0 = by * 32;
        for (int i = ty; i < 32; i += 8) {
            int r = r0 + i, c = c0 + tx;
            tile[i][tx] = (r < R && c < C) ? f2bf(in[(size_t)r * C + c]) : (unsigned short)0;
        }
        __syncthreads();
        for (int i = ty; i < 32; i += 8) {
            int c = c0 + i, r = r0 + tx;
            if (r < R && c < C) out[(size_t)c * ldo + r] = tile[tx][i];
        }
    } else {
        int g = blk - 6240;
        const float* src = (g == 0) ? ca : (g == 1) ? cb : cc;
        unsigned short* dst = clsb + g * 4096;
        for (int i = t; i < 4096; i += 256) dst[i] = f2bf(src[i]);
    }
}

// ------- 8-phase 256-row MFMA GEMM (w1 + GELU), unchanged from round 5 -------
#define EPI_GELU_BF16  0

template <int EPI, int BN>
__global__ __launch_bounds__(512, 1) void gemm_8p(
        const unsigned short* __restrict__ A, int lda,
        const unsigned short* __restrict__ BT, int ldb,
        const float* __restrict__ bias,
        const unsigned short* __restrict__ xres,
        unsigned short* __restrict__ Cout, int ldc, int K) {
    constexpr int NFC = BN / 64;
    constexpr int FCH = NFC / 2;
    constexpr int NLB = BN / 128;
    constexpr int BH  = BN / 2;
    __shared__ unsigned short Ab[2][2][128 * 64] __attribute__((aligned(16)));
    __shared__ unsigned short Bb[2][2][BH * 64] __attribute__((aligned(16)));
    const int t = threadIdx.x;
    const int lane = t & 63, w = t >> 6;
    const int quad = lane >> 4, l16 = lane & 15;
    const int wmh = w >> 2;
    const int wn  = w & 3;
    const int bhalf = wn >> 1, bbase = (wn & 1) * (BN / 4);
    const long tileM = (long)blockIdx.x * 256;
    const long tileN = (long)blockIdx.y * BN;

    const int rl = lane >> 3;
    const int cl = ((lane & 7) ^ rl) * 8;

    const unsigned short* pa[2][2];
    #pragma unroll
    for (int h = 0; h < 2; ++h)
        #pragma unroll
        for (int q = 0; q < 2; ++q)
            pa[h][q] = A + (tileM + h * 128 + w * 16 + q * 8 + rl) * (size_t)lda + cl;
    const unsigned short* pb[2][2];
    #pragma unroll
    for (int h = 0; h < 2; ++h) {
        if constexpr (NLB == 2) {
            #pragma unroll
            for (int q = 0; q < 2; ++q)
                pb[h][q] = BT + (tileN + h * BH + w * 16 + q * 8 + rl) * (size_t)ldb + cl;
        } else {
            pb[h][0] = BT + (tileN + h * BH + w * 8 + rl) * (size_t)ldb + cl;
        }
    }
    int kA = 0, kB = 0;

    auto stageA = [&](int buf, int h) {
        glds16(pa[h][0] + kA, &Ab[buf][h][(w * 2 + 0) * 512]);
        glds16(pa[h][1] + kA, &Ab[buf][h][(w * 2 + 1) * 512]);
    };
    auto stageB = [&](int buf, int h) {
        if constexpr (NLB == 2) {
            glds16(pb[h][0] + kB, &Bb[buf][h][(w * 2 + 0) * 512]);
            glds16(pb[h][1] + kB, &Bb[buf][h][(w * 2 + 1) * 512]);
        } else {
            glds16(pb[h][0] + kB, &Bb[buf][h][w * 512]);
        }
    };

    const int xl = l16 & 7;
    const int ak0 = l16 * 64 + (((quad    ) ^ xl) * 8);
    const int ak1 = l16 * 64 + (((quad + 4) ^ xl) * 8);

    stageA(0, 0); stageA(0, 1); kA = 64;
    stageB(0, 0); stageB(0, 1); kB = 64;
    stageB(1, 0); stageB(1, 1); kB = 128;

    v4f acc[8][NFC] = {};
    const int nt = K >> 6;

    asm volatile("s_waitcnt vmcnt(%0)" :: "i"(2 * NLB) : "memory");
    __builtin_amdgcn_s_barrier();

    for (int tt = 0; tt < nt; ++tt) {
        const int bi = tt & 1;
        const unsigned short* Ah = &Ab[bi][wmh][0];
        const unsigned short* Bh = &Bb[bi][bhalf][bbase * 64];
        v8s af[4][2], bf[NFC][2];

        #pragma unroll
        for (int fr = 0; fr < 4; ++fr) {
            af[fr][0] = *(const v8s*)(Ah + fr * 1024 + ak0);
            af[fr][1] = *(const v8s*)(Ah + fr * 1024 + ak1);
        }
        #pragma unroll
        for (int fc = 0; fc < FCH; ++fc) {
            bf[fc][0] = *(const v8s*)(Bh + fc * 1024 + ak0);
            bf[fc][1] = *(const v8s*)(Bh + fc * 1024 + ak1);
        }
        if (tt + 1 < nt) stageA(bi ^ 1, 0);
        __builtin_amdgcn_s_barrier();
        asm volatile("s_waitcnt lgkmcnt(0)" ::: "memory");
        __builtin_amdgcn_s_setprio(1);
        #pragma unroll
        for (int fr = 0; fr < 4; ++fr)
            #pragma unroll
            for (int fc = 0; fc < FCH; ++fc) {
                acc[fr][fc] = __builtin_amdgcn_mfma_f32_16x16x32_bf16(bf[fc][0], af[fr][0], acc[fr][fc], 0, 0, 0);
                acc[fr][fc] = __builtin_amdgcn_mfma_f32_16x16x32_bf16(bf[fc][1], af[fr][1], acc[fr][fc], 0, 0, 0);
            }
        __builtin_amdgcn_s_setprio(0);
        __builtin_amdgcn_s_barrier();

        #pragma unroll
        for (int fc = FCH; fc < NFC; ++fc) {
            bf[fc][0] = *(const v8s*)(Bh + fc * 1024 + ak0);
            bf[fc][1] = *(const v8s*)(Bh + fc * 1024 + ak1);
        }
        if (tt + 1 < nt) stageA(bi ^ 1, 1);
        kA += 64;
        __builtin_amdgcn_s_barrier();
        asm volatile("s_waitcnt lgkmcnt(0)" ::: "memory");
        __builtin_amdgcn_s_setprio(1);
        #pragma unroll
        for (int fr = 0; fr < 4; ++fr)
            #pragma unroll
            for (int fc = FCH; fc < NFC; ++fc) {
                acc[fr][fc] = __builtin_amdgcn_mfma_f32_16x16x32_bf16(bf[fc][0], af[fr][0], acc[fr][fc], 0, 0, 0);
                acc[fr][fc] = __builtin_amdgcn_mfma_f32_16x16x32_bf16(bf[fc][1], af[fr][1], acc[fr][fc], 0, 0, 0);
            }
        __builtin_amdgcn_s_setprio(0);
        __builtin_amdgcn_s_barrier();

        #pragma unroll
        for (int fr = 0; fr < 4; ++fr) {
            af[fr][0] = *(const v8s*)(Ah + (fr + 4) * 1024 + ak0);
            af[fr][1] = *(const v8s*)(Ah + (fr + 4) * 1024 + ak1);
        }
        if (tt + 2 < nt) stageB(bi, 0);
        __builtin_amdgcn_s_barrier();
        asm volatile("s_waitcnt lgkmcnt(0)" ::: "memory");
        __builtin_amdgcn_s_setprio(1);
        #pragma unroll
        for (int fr = 0; fr < 4; ++fr)
            #pragma unroll
            for (int fc = 0; fc < FCH; ++fc) {
                acc[fr + 4][fc] = __builtin_amdgcn_mfma_f32_16x16x32_bf16(bf[fc][0], af[fr][0], acc[fr + 4][fc], 0, 0, 0);
                acc[fr + 4][fc] = __builtin_amdgcn_mfma_f32_16x16x32_bf16(bf[fc][1], af[fr][1], acc[fr + 4][fc], 0, 0, 0);
            }
        __builtin_amdgcn_s_setprio(0);
        __builtin_amdgcn_s_barrier();

        if (tt + 2 < nt) stageB(bi, 1);
        kB += 64;
        if (tt + 2 < nt)
            asm volatile("s_waitcnt vmcnt(%0)" :: "i"(2 * NLB) : "memory");
        else if (tt + 1 < nt)
            asm volatile("s_waitcnt vmcnt(0)" ::: "memory");
        __builtin_amdgcn_s_barrier();
        __builtin_amdgcn_s_setprio(1);
        #pragma unroll
        for (int fr = 0; fr < 4; ++fr)
            #pragma unroll
            for (int fc = FCH; fc < NFC; ++fc) {
                acc[fr + 4][fc] = __builtin_amdgcn_mfma_f32_16x16x32_bf16(bf[fc][0], af[fr][0], acc[fr + 4][fc], 0, 0, 0);
                acc[fr + 4][fc] = __builtin_amdgcn_mfma_f32_16x16x32_bf16(bf[fc][1], af[fr][1], acc[fr + 4][fc], 0, 0, 0);
            }
        __builtin_amdgcn_s_setprio(0);
        __builtin_amdgcn_s_barrier();
    }

    #pragma unroll
    for (int fr = 0; fr < 8; ++fr) {
        long m = tileM + wmh * 128 + fr * 16 + l16;
        #pragma unroll
        for (int fc = 0; fc < NFC; ++fc) {
            long n0 = tileN + wn * (BN / 4) + fc * 16 + quad * 4;
            float4 bi4 = *(const float4*)&bias[n0];
            const float* bip = (const float*)&bi4;
            unsigned short pk[4];
            #pragma unroll
            for (int r = 0; r < 4; ++r)
                pk[r] = f2bf(fast_gelu(acc[fr][fc][r] + bip[r]));
            *(ushort4*)&Cout[m * ldc + n0] = *(ushort4*)pk;
        }
    }
}

// ------- w2-GEMM + residual + fused LayerNorm epilogue -------
// BM=64 full-row blocks (BN=512 = whole output row), grid 256x1, 512 thr.
// 2-phase dbuf glds staging, counted vmcnt (NL=5 for A-waves 0-3, 4 else).
// Epilogue: x_new = acc+b2+x -> write x (bf16); LN stats via quad-shuffle +
// 2KB LDS cross-wave reduce; write hl = LN(x_new)*g+b (layer LN or role LN).
__global__ __launch_bounds__(512) void gemm_w2ln(
        const unsigned short* __restrict__ A,      // Hb [16384][1024]
        const unsigned short* __restrict__ BT,     // w2T [512][1024]
        const float* __restrict__ bias,            // b2 [512]
        unsigned short* __restrict__ x,            // residual in / out
        const float* __restrict__ lnw, const float* __restrict__ lnb,
        unsigned short* __restrict__ hl) {
    constexpr int NT = 32;                         // K=1024 / BK=32
    __shared__ unsigned short As[2][64 * 32] __attribute__((aligned(16)));
    __shared__ unsigned short Bs[2][512 * 32] __attribute__((aligned(16)));
    __shared__ float sbuf[64][4];
    __shared__ float s2buf[64][4];
    const int t = threadIdx.x;
    const int lane = t & 63, w = t >> 6;
    const int quad = lane >> 4, l16 = lane & 15;
    const int wm = (w >> 2) * 32;                  // 0 / 32
    const int wnq = w & 3;
    const int wn = wnq * 128;
    const long tileM = (long)blockIdx.x * 64;

    const int lr = lane >> 2, lc = (lane & 3) * 8;
    const unsigned short* gA = A + (tileM + (w & 3) * 16 + lr) * 1024 + lc;  // waves 0-3 only
    const unsigned short* gB[4];
    #pragma unroll
    for (int q = 0; q < 4; ++q)
        gB[q] = BT + (w * 64 + q * 16 + lr) * 1024 + lc;
    int koff = 0;

    auto stage = [&](int buf) {
        if (w < 4) glds16(gA + koff, &As[buf][w * 512]);
        #pragma unroll
        for (int q = 0; q < 4; ++q)
            glds16(gB[q] + koff, &Bs[buf][(w * 4 + q) * 512]);
        koff += 32;
    };

    v4f acc[2][8] = {};
    stage(0);
    int cur = 0;
    for (int kk = 0; kk < NT; ++kk) {
        if (kk + 1 < NT) {
            stage(cur ^ 1);
            if (w < 4) asm volatile("s_waitcnt vmcnt(5)" ::: "memory");
            else       asm volatile("s_waitcnt vmcnt(4)" ::: "memory");
        } else {
            asm volatile("s_waitcnt vmcnt(0)" ::: "memory");
        }
        asm volatile("s_barrier" ::: "memory");
        v8s af[2], bfr[8];
        #pragma unroll
        for (int i = 0; i < 2; ++i)
            af[i] = *(const v8s*)&As[cur][(wm + i * 16 + l16) * 32 + quad * 8];
        #pragma unroll
        for (int j = 0; j < 8; ++j)
            bfr[j] = *(const v8s*)&Bs[cur][(wn + j * 16 + l16) * 32 + quad * 8];
        #pragma unroll
        for (int i = 0; i < 2; ++i)
            #pragma unroll
            for (int j = 0; j < 8; ++j)
                acc[i][j] = __builtin_amdgcn_mfma_f32_16x16x32_bf16(bfr[j], af[i], acc[i][j], 0, 0, 0);
        if (kk + 1 < NT)
            asm volatile("s_barrier" ::: "memory");
        cur ^= 1;
    }

    // ---- epilogue: residual add, x write, LN stats ----
    float s1v[2] = {0.f, 0.f}, s2v[2] = {0.f, 0.f};
    #pragma unroll
    for (int i = 0; i < 2; ++i) {
        long m = tileM + wm + i * 16 + l16;
        #pragma unroll
        for (int j = 0; j < 8; ++j) {
            int n0 = wn + j * 16 + quad * 4;
            float4 bi4 = *(const float4*)&bias[n0];
            const float* bip = (const float*)&bi4;
            ushort4 xr4 = *(const ushort4*)&x[m * 512 + n0];
            const unsigned short* xp = (const unsigned short*)&xr4;
            unsigned short pk[4];
            #pragma unroll
            for (int r = 0; r < 4; ++r) {
                float v = acc[i][j][r] + bip[r] + bf2f(xp[r]);
                acc[i][j][r] = v;                    // keep for LN pass
                s1v[i] += v; s2v[i] += v * v;
                pk[r] = f2bf(v);
            }
            *(ushort4*)&x[m * 512 + n0] = *(ushort4*)pk;
        }
    }
    // reduce across the 4 quads (lanes same l16)
    #pragma unroll
    for (int i = 0; i < 2; ++i) {
        s1v[i] += __shfl_xor(s1v[i], 16); s1v[i] += __shfl_xor(s1v[i], 32);
        s2v[i] += __shfl_xor(s2v[i], 16); s2v[i] += __shfl_xor(s2v[i], 32);
    }
    if (quad == 0) {
        #pragma unroll
        for (int i = 0; i < 2; ++i) {
            int r = wm + i * 16 + l16;
            sbuf[r][wnq] = s1v[i];
            s2buf[r][wnq] = s2v[i];
        }
    }
    __syncthreads();
    #pragma unroll
    for (int i = 0; i < 2; ++i) {
        int r = wm + i * 16 + l16;
        long m = tileM + r;
        float s1 = sbuf[r][0] + sbuf[r][1] + sbuf[r][2] + sbuf[r][3];
        float s2 = s2buf[r][0] + s2buf[r][1] + s2buf[r][2] + s2buf[r][3];
        float mean = s1 * (1.0f / 512.0f);
        float rinv = 1.0f / sqrtf(s2 * (1.0f / 512.0f) - mean * mean + 1e-5f);
        #pragma unroll
        for (int j = 0; j < 8; ++j) {
            int n0 = wn + j * 16 + quad * 4;
            float4 g4 = *(const float4*)&lnw[n0];
            float4 b4 = *(const float4*)&lnb[n0];
            const float* gp = (const float*)&g4;
            const float* bp = (const float*)&b4;
            unsigned short pk[4];
            #pragma unroll
            for (int r2 = 0; r2 < 4; ++r2)
                pk[r2] = f2bf((acc[i][j][r2] - mean) * rinv * gp[r2] + bp[r2]);
            *(ushort4*)&hl[m * 512 + n0] = *(ushort4*)pk;
        }
    }
}

// ------- fused tanh-GEMM + class-GEMM, R2-structure K-loop, TM=128 -------
__global__ __launch_bounds__(256) void tanh_class_kernel(
        const unsigned short* __restrict__ A,
        const unsigned short* __restrict__ WT,
        const unsigned short* __restrict__ cls,
        unsigned short* __restrict__ uu) {
    __shared__ unsigned short As[128][40] __attribute__((aligned(16)));
    __shared__ unsigned short Bs[64][40] __attribute__((aligned(16)));
    __shared__ unsigned short P[128 * 72] __attribute__((aligned(16)));
    const int t = threadIdx.x;
    const int lane = t & 63, wave = t >> 6;
    const int quad = lane >> 4, l16 = lane & 15;
    const int wm = (wave >> 1) * 64, wn = (wave & 1) * 32;
    const long tileM = (long)blockIdx.x * 128;
    const int g = blockIdx.y;
    const int arow = t >> 2, acol = (t & 3) * 8;

    const unsigned short* BT = WT + g * 32768;
    v8s cf[2][2];
    #pragma unroll
    for (int ks = 0; ks < 2; ++ks)
        #pragma unroll
        for (int j = 0; j < 2; ++j)
            cf[ks][j] = *(const v8s*)&cls[g * 4096 + (wn + j * 16 + l16) * 64 + ks * 32 + quad * 8];

    const unsigned short* gA0 = A + (tileM + arow) * 512 + acol;
    const unsigned short* gA1 = gA0 + 64 * 512;
    const unsigned short* gB0 = BT + arow * 512 + acol;

    v4f acc[4][2] = {};
    uint4 a0, a1, b0;
    a0 = *(const uint4*)gA0; a1 = *(const uint4*)gA1; gA0 += 32; gA1 += 32;
    b0 = *(const uint4*)gB0; gB0 += 32;
    *(uint4*)&As[arow][acol] = a0;
    *(uint4*)&As[arow + 64][acol] = a1;
    *(uint4*)&Bs[arow][acol] = b0;

    for (int kk = 0; kk < 16; ++kk) {
        __syncthreads();
        const bool more = kk < 15;
        if (more) {
            a0 = *(const uint4*)gA0; a1 = *(const uint4*)gA1; gA0 += 32; gA1 += 32;
            b0 = *(const uint4*)gB0; gB0 += 32;
        }
        v8s af[4], bfr[2];
        #pragma unroll
        for (int i = 0; i < 4; ++i) af[i] = *(const v8s*)&As[wm + i * 16 + l16][quad * 8];
        #pragma unroll
        for (int j = 0; j < 2; ++j) bfr[j] = *(const v8s*)&Bs[wn + j * 16 + l16][quad * 8];
        #pragma unroll
        for (int i = 0; i < 4; ++i)
            #pragma unroll
            for (int j = 0; j < 2; ++j)
                acc[i][j] = __builtin_amdgcn_mfma_f32_16x16x32_bf16(bfr[j], af[i], acc[i][j], 0, 0, 0);
        __syncthreads();
        if (more) {
            *(uint4*)&As[arow][acol] = a0;
            *(uint4*)&As[arow + 64][acol] = a1;
            *(uint4*)&Bs[arow][acol] = b0;
        }
    }

    #pragma unroll
    for (int i = 0; i < 4; ++i) {
        int m = wm + i * 16 + l16;
        #pragma unroll
        for (int j = 0; j < 2; ++j) {
            int n0 = wn + j * 16 + quad * 4;
            unsigned short pk[4];
            #pragma unroll
            for (int r = 0; r < 4; ++r) pk[r] = f2bf(fast_tanh(acc[i][j][r]));
            *(ushort4*)&P[m * 72 + n0] = *(ushort4*)pk;
        }
    }
    __syncthreads();

    v4f acc2[4][2] = {};
    #pragma unroll
    for (int ks = 0; ks < 2; ++ks) {
        v8s paf[4];
        #pragma unroll
        for (int i = 0; i < 4; ++i)
            paf[i] = *(const v8s*)&P[(wm + i * 16 + l16) * 72 + ks * 32 + quad * 8];
        #pragma unroll
        for (int i = 0; i < 4; ++i)
            #pragma unroll
            for (int j = 0; j < 2; ++j)
                acc2[i][j] = __builtin_amdgcn_mfma_f32_16x16x32_bf16(cf[ks][j], paf[i], acc2[i][j], 0, 0, 0);
    }

    #pragma unroll
    for (int i = 0; i < 4; ++i) {
        long m = tileM + wm + i * 16 + l16;
        #pragma unroll
        for (int j = 0; j < 2; ++j) {
            int c0 = wn + j * 16 + quad * 4;
            unsigned short pk[4];
            #pragma unroll
            for (int r = 0; r < 4; ++r) pk[r] = f2bf(acc2[i][j][r]);
            *(ushort4*)&uu[m * 192 + g * 64 + c0] = *(ushort4*)pk;
        }
    }
}

// ------- exact ordered-triplet scan pass 1 -------
__global__ __launch_bounds__(64) void scan_part_kernel(const unsigned short* __restrict__ u,
                                                       float* __restrict__ part) {
    int b = blockIdx.x, seg = blockIdx.y;
    int c = threadIdx.x;
    int l0 = seg * 32;
    int l1 = l0 + 32; if (l1 > 2047) l1 = 2047;
    float sA = 0.f, sB = 0.f, sC = 0.f, T = 0.f, M = 0.f, U = 0.f;
    const unsigned short* base = u + ((size_t)b * LSEQ + l0) * 192 + c;
    for (int l = l0; l < l1; ++l) {
        float ua = bf2f(base[0]), ub = bf2f(base[64]), uc = bf2f(base[128]);
        base += 192;
        U += uc * T;
        M += uc * sB;
        T += ub * sA;
        sA += ua; sB += ub; sC += uc;
    }
    float* p = part + ((size_t)(b * 64 + seg)) * 384 + c;
    p[0] = sA; p[64] = sB; p[128] = sC; p[192] = T; p[256] = M; p[320] = U;
}

// ------- merged: segment combine + final LN + Wq GEMV -------
__global__ __launch_bounds__(64) void combine_final_kernel(const float* __restrict__ part,
        const unsigned short* __restrict__ x,
        const float* __restrict__ qw, const float* __restrict__ qb,
        const float* __restrict__ Wq, const float* __restrict__ bq,
        float* __restrict__ out, float inv_denom) {
    int b = blockIdx.x;
    int c = threadIdx.x;
    const float* p = part + (size_t)b * 64 * 384 + c;
    float A = p[0], B = p[64], Tt = p[192], Mt = p[256], Ut = p[320];
    for (int seg = 1; seg < 64; ++seg) {
        const float* q2 = p + seg * 384;
        float a2 = q2[0], b2 = q2[64], c2 = q2[128], t2 = q2[192], m2 = q2[256], u2 = q2[320];
        float Un = Ut + u2 + c2 * Tt + A * m2;
        float Tn = Tt + t2 + A * b2;
        float Mn = Mt + m2 + B * c2;
        A += a2; B += b2;
        Ut = Un; Tt = Tn; Mt = Mn;
    }
    __shared__ float q[512];
    __shared__ float mv[2];
    const unsigned short* xr = x + ((size_t)b * LSEQ + (LSEQ - 1)) * 512;
    float s1 = 0.f, s2 = 0.f;
    for (int i = c; i < 512; i += 64) { float v = bf2f(xr[i]); q[i] = v; s1 += v; s2 += v * v; }
    #pragma unroll
    for (int o = 32; o > 0; o >>= 1) { s1 += __shfl_down(s1, o); s2 += __shfl_down(s2, o); }
    if (c == 0) {
        float m = s1 * (1.0f / 512.0f);
        float var = s2 * (1.0f / 512.0f) - m * m;
        mv[0] = m; mv[1] = 1.0f / sqrtf(var + 1e-5f);
    }
    __syncthreads();
    float m = mv[0], r = mv[1];
    for (int i = c; i < 512; i += 64) q[i] = (q[i] - m) * r * qw[i] + qb[i];
    __syncthreads();
    float acc = 0.f;
    for (int d = 0; d < 512; ++d) acc += q[d] * Wq[d * 64 + c];
    out[b * 64 + c] = Ut * inv_denom + acc + bq[c];
}

extern "C" void kernel_launch(void* const* d_in, const int* in_sizes, int n_in,
                              void* d_out, int out_size, void* d_ws, size_t ws_size,
                              hipStream_t stream) {
    const int*   token_ids   = (const int*)d_in[0];
    const float* tok_emb     = (const float*)d_in[1];
    const float* pos_emb     = (const float*)d_in[2];
    const float* stem_ln_w   = (const float*)d_in[3];
    const float* stem_ln_b   = (const float*)d_in[4];
    const float* stem_w1     = (const float*)d_in[5];
    const float* stem_b1     = (const float*)d_in[6];
    const float* stem_w2     = (const float*)d_in[7];
    const float* stem_b2     = (const float*)d_in[8];
    const float* role_ln_w   = (const float*)d_in[9];
    const float* role_ln_b   = (const float*)d_in[10];
    const float* Wa          = (const float*)d_in[11];
    const float* Wb          = (const float*)d_in[12];
    const float* Wc          = (const float*)d_in[13];
    const float* class_a     = (const float*)d_in[14];
    const float* class_b     = (const float*)d_in[15];
    const float* class_c     = (const float*)d_in[16];
    const float* query_ln_w  = (const float*)d_in[17];
    const float* query_ln_b  = (const float*)d_in[18];
    const float* Wq          = (const float*)d_in[19];
    const float* bq          = (const float*)d_in[20];
    float* out = (float*)d_out;

    char* wsb = (char*)d_ws;
    unsigned short* x    = (unsigned short*)(wsb);              // 16,777,216
    unsigned short* hl   = (unsigned short*)(wsb + 16777216);   // 16,777,216
    unsigned short* Hb   = (unsigned short*)(wsb + 33554432);   // 33,554,432
    unsigned short* uu   = (unsigned short*)(wsb + 67108864);   // 6,291,456
    float* part          = (float*)(wsb + 73400320);            // 786,432
    unsigned short* w1T  = (unsigned short*)(wsb + 74188800);   // 2,097,152
    unsigned short* w2T  = (unsigned short*)(wsb + 76285952);   // 2,097,152
    unsigned short* wabcT= (unsigned short*)(wsb + 78383104);   // 196,608
    unsigned short* clsb = (unsigned short*)(wsb + 78579712);   // 24,576

    setup_kernel<<<6243, 256, 0, stream>>>(token_ids, tok_emb, pos_emb,
        stem_ln_w, stem_ln_b, x, hl,
        stem_w1, stem_w2, Wa, Wb, Wc, class_a, class_b, class_c,
        w1T, w2T, wabcT, clsb);

    for (int i = 0; i < 2; ++i) {
        gemm_8p<EPI_GELU_BF16, 256><<<dim3(64, 4), 512, 0, stream>>>(
            hl, 512, w1T + i * 524288, 512, stem_b1 + i * 1024, nullptr, Hb, 1024, 512);
        // w2 GEMM + residual + fused LN: layer 0 -> stem LN1, layer 1 -> role LN
        gemm_w2ln<<<256, 512, 0, stream>>>(
            Hb, w2T + i * 524288, stem_b2 + i * 512, x,
            (i == 0) ? stem_ln_w + 512 : role_ln_w,
            (i == 0) ? stem_ln_b + 512 : role_ln_b,
            hl);
    }

    tanh_class_kernel<<<dim3(128, 3), 256, 0, stream>>>(hl, wabcT, clsb, uu);

    scan_part_kernel<<<dim3(NB, 64), 64, 0, stream>>>(uu, part);

    float inv_denom = (float)(6.0 / (2047.0 * 2046.0 * 2045.0));
    combine_final_kernel<<<NB, 64, 0, stream>>>(part, x, query_ln_w, query_ln_b,
                                                Wq, bq, out, inv_denom);
}

// Round 7
// 346.552 us; speedup vs baseline: 1.0151x; 1.0151x over previous
//
#include <hip/hip_runtime.h>

#define NROWS 16384   // B*L
#define LSEQ  2048
#define NB    8

typedef short v8s __attribute__((ext_vector_type(8)));
typedef float v4f __attribute__((ext_vector_type(4)));

__device__ __forceinline__ unsigned short f2bf(float f) {
    unsigned int u = __float_as_uint(f);
    return (unsigned short)((u + 0x7fffu + ((u >> 16) & 1u)) >> 16);
}
__device__ __forceinline__ float bf2f(unsigned short u) {
    return __uint_as_float(((unsigned int)u) << 16);
}

// async global->LDS, 16B per lane; LDS dest is wave-uniform base + lane*16
__device__ __forceinline__ void glds16(const void* g, void* l) {
    __builtin_amdgcn_global_load_lds(
        (__attribute__((address_space(1))) void*)g,
        (__attribute__((address_space(3))) void*)l,
        16, 0, 0);
}

// fast exact-GELU: Abramowitz-Stegun 5-term erf, |err|<1.5e-7
__device__ __forceinline__ float fast_gelu(float v) {
    float z = fabsf(v) * 0.70710678118654752f;
    float t = __builtin_amdgcn_rcpf(1.0f + 0.3275911f * z);
    float poly = t * (0.254829592f + t * (-0.284496736f + t * (1.421413741f +
                 t * (-1.453152027f + t * 1.061405429f))));
    float erfz = 1.0f - poly * __expf(-z * z);
    float er = copysignf(erfz, v);
    return 0.5f * v * (1.0f + er);
}
__device__ __forceinline__ float fast_tanh(float y) {
    float e = __expf(2.0f * y);
    return (e - 1.0f) * __builtin_amdgcn_rcpf(e + 1.0f);
}

// XCD row-swizzle: block b (of 4096, 4 rows each) -> rows of 128-row tile T with
// T%8 == b%8, so the producer's XCD matches the GEMM reader's XCD.
__device__ __forceinline__ long swizzled_row(int b, int wave) {
    int T = (b & 7) + (((b >> 3) & 15) << 3);   // 0..127, T%8 == b%8
    int chunk = b >> 7;                          // 0..31
    return (long)T * 128 + chunk * 4 + wave;
}

// ------- merged setup:
//   blocks 0..4095     : embed (XCD-swizzled) -> x + rowstat0 (s1,s2)
//   blocks 4096..6239  : weight transposes; gamma FOLDED into w1T / wabcT
//   blocks 6240..6242  : class bf16 converts
//   blocks 6243..6250  : w1 LN colsum constants c1,c2  (2 layers x 1024 cols)
//   block  6251        : wa/wb/wc LN colsum constants c1a,c2a (192)
__global__ __launch_bounds__(256) void setup_kernel(
        const int* __restrict__ ids,
        const float* __restrict__ tok, const float* __restrict__ pos,
        const float* __restrict__ g0, const float* __restrict__ b0,   // stem_ln_w/b [2][512]
        const float* __restrict__ rolew, const float* __restrict__ roleb,
        const float* __restrict__ b1all,                              // stem_b1 [2][1024]
        unsigned short* __restrict__ x, float* __restrict__ rowstat0,
        const float* __restrict__ w1, const float* __restrict__ w2,
        const float* __restrict__ wa, const float* __restrict__ wb, const float* __restrict__ wc,
        const float* __restrict__ ca, const float* __restrict__ cb, const float* __restrict__ cc,
        unsigned short* __restrict__ w1T, unsigned short* __restrict__ w2T,
        unsigned short* __restrict__ wabcT, unsigned short* __restrict__ clsb,
        float* __restrict__ c1buf, float* __restrict__ c2buf,
        float* __restrict__ c1a, float* __restrict__ c2a) {
    int blk = blockIdx.x;
    int t = threadIdx.x;
    if (blk < 4096) {
        int wave = t >> 6, lane = t & 63;
        long row = swizzled_row(blk, wave);
        int l = (int)(row & (LSEQ - 1));
        int id = ids[row];
        int d = lane * 8;
        float4 t0 = *(const float4*)(tok + (size_t)id * 512 + d);
        float4 t1 = *(const float4*)(tok + (size_t)id * 512 + d + 4);
        float4 p0 = *(const float4*)(pos + (size_t)l * 512 + d);
        float4 p1 = *(const float4*)(pos + (size_t)l * 512 + d + 4);
        float a[8] = {t0.x + p0.x, t0.y + p0.y, t0.z + p0.z, t0.w + p0.w,
                      t1.x + p1.x, t1.y + p1.y, t1.z + p1.z, t1.w + p1.w};
        unsigned int xp[4];
        #pragma unroll
        for (int i = 0; i < 4; ++i)
            xp[i] = (unsigned int)f2bf(a[2 * i]) | ((unsigned int)f2bf(a[2 * i + 1]) << 16);
        *(uint4*)(x + row * 512 + d) = *(uint4*)xp;
        float s = 0.f, s2 = 0.f;
        #pragma unroll
        for (int i = 0; i < 8; ++i) { s += a[i]; s2 += a[i] * a[i]; }
        #pragma unroll
        for (int o = 32; o > 0; o >>= 1) { s += __shfl_down(s, o); s2 += __shfl_down(s2, o); }
        if (lane == 0) {
            rowstat0[row * 2] = s;
            rowstat0[row * 2 + 1] = s2;
        }
    } else if (blk < 6240) {
        int id = blk - 4096;
        int tx = t & 31, ty = t >> 5;
        const float* in; unsigned short* out; int R, C, bx, by, ldo;
        const float* gfold = nullptr;    // row-index (k) gamma fold
        if (id < 1024) {
            int l = id >> 9, r = id & 511;
            in = w1 + l * 524288; out = w1T + l * 524288;
            R = 512; C = 1024; bx = r & 31; by = r >> 5; ldo = 512;
            gfold = g0 + l * 512;
        } else if (id < 2048) {
            int l = (id - 1024) >> 9, r = (id - 1024) & 511;
            in = w2 + l * 524288; out = w2T + l * 524288;
            R = 1024; C = 512; bx = r & 15; by = r >> 4; ldo = 1024;
        } else {
            int g = (id - 2048) >> 5, r = (id - 2048) & 31;
            in = (g == 0) ? wa : (g == 1) ? wb : wc;
            out = wabcT + g * 32768;
            R = 512; C = 64; bx = r & 1; by = r >> 1; ldo = 512;
            gfold = rolew;
        }
        __shared__ unsigned short tile[32][33];
        int c0 = bx * 32, r0 = by * 32;
        for (int i = ty; i < 32; i += 8) {
            int r = r0 + i, c = c0 + tx;
            float v = (r < R && c < C) ? in[(size_t)r * C + c] : 0.f;
            if (gfold && r < R) v *= gfold[r];
            tile[i][tx] = f2bf(v);
        }
        __syncthreads();
        for (int i = ty; i < 32; i += 8) {
            int c = c0 + i, r = r0 + tx;
            if (r < R && c < C) out[(size_t)c * ldo + r] = tile[tx][i];
        }
    } else if (blk < 6243) {
        int g = blk - 6240;
        const float* src = (g == 0) ? ca : (g == 1) ? cb : cc;
        unsigned short* dst = clsb + g * 4096;
        for (int i = t; i < 4096; i += 256) dst[i] = f2bf(src[i]);
    } else if (blk < 6251) {
        // w1 colsums: c1[l][n] = sum_k g_l[k] w1_l[k,n]; c2 = sum_k b_l[k] w1 + b1_l[n]
        int c = blk - 6243;
        int l = c >> 2, nb = c & 3;
        int n = nb * 256 + t;
        const float* W = w1 + l * 524288;
        const float* g = g0 + l * 512;
        const float* b = b0 + l * 512;
        float a1 = 0.f, a2 = 0.f;
        for (int k = 0; k < 512; ++k) {
            float w = W[(size_t)k * 1024 + n];
            a1 += g[k] * w;
            a2 += b[k] * w;
        }
        c1buf[l * 1024 + n] = a1;
        c2buf[l * 1024 + n] = a2 + b1all[l * 1024 + n];
    } else {
        // abc colsums: 192 entries (3 groups x 64)
        if (t < 192) {
            int gi = t >> 6, r = t & 63;
            const float* W = (gi == 0) ? wa : (gi == 1) ? wb : wc;
            float a1 = 0.f, a2 = 0.f;
            for (int k = 0; k < 512; ++k) {
                float w = W[(size_t)k * 64 + r];
                a1 += rolew[k] * w;
                a2 += roleb[k] * w;
            }
            c1a[t] = a1;
            c2a[t] = a2;
        }
    }
}

// ------- w1 GEMM: 8-phase BM=256 BN=256, reads raw x, LN folded -------
// h = gelu( rinv*acc - rinv*mu*c1[n] + c2[n] )
// SM=0: stats = rowstat0[m][2] direct.  SM=1: stats = rowpart[m][4][2], sum 4.
template <int SM>
__global__ __launch_bounds__(512, 1) void gemm_w1(
        const unsigned short* __restrict__ A,      // x [16384][512]
        const unsigned short* __restrict__ BT,     // g-folded w1T [1024][512]
        const float* __restrict__ c1, const float* __restrict__ c2,
        const float* __restrict__ stats,
        unsigned short* __restrict__ Cout) {       // Hb [16384][1024]
    constexpr int BN = 256, NFC = 4, FCH = 2, NLB = 2, BH = 128;
    constexpr int lda = 512, ldb = 512, ldc = 1024, K = 512;
    __shared__ unsigned short Ab[2][2][128 * 64] __attribute__((aligned(16)));
    __shared__ unsigned short Bb[2][2][BH * 64] __attribute__((aligned(16)));
    const int t = threadIdx.x;
    const int lane = t & 63, w = t >> 6;
    const int quad = lane >> 4, l16 = lane & 15;
    const int wmh = w >> 2;
    const int wn  = w & 3;
    const int bhalf = wn >> 1, bbase = (wn & 1) * (BN / 4);
    const long tileM = (long)blockIdx.x * 256;
    const long tileN = (long)blockIdx.y * BN;

    const int rl = lane >> 3;
    const int cl = ((lane & 7) ^ rl) * 8;

    const unsigned short* pa[2][2];
    #pragma unroll
    for (int h = 0; h < 2; ++h)
        #pragma unroll
        for (int q = 0; q < 2; ++q)
            pa[h][q] = A + (tileM + h * 128 + w * 16 + q * 8 + rl) * (size_t)lda + cl;
    const unsigned short* pb[2][2];
    #pragma unroll
    for (int h = 0; h < 2; ++h)
        #pragma unroll
        for (int q = 0; q < 2; ++q)
            pb[h][q] = BT + (tileN + h * BH + w * 16 + q * 8 + rl) * (size_t)ldb + cl;
    int kA = 0, kB = 0;

    auto stageA = [&](int buf, int h) {
        glds16(pa[h][0] + kA, &Ab[buf][h][(w * 2 + 0) * 512]);
        glds16(pa[h][1] + kA, &Ab[buf][h][(w * 2 + 1) * 512]);
    };
    auto stageB = [&](int buf, int h) {
        glds16(pb[h][0] + kB, &Bb[buf][h][(w * 2 + 0) * 512]);
        glds16(pb[h][1] + kB, &Bb[buf][h][(w * 2 + 1) * 512]);
    };

    const int xl = l16 & 7;
    const int ak0 = l16 * 64 + (((quad    ) ^ xl) * 8);
    const int ak1 = l16 * 64 + (((quad + 4) ^ xl) * 8);

    stageA(0, 0); stageA(0, 1); kA = 64;
    stageB(0, 0); stageB(0, 1); kB = 64;
    stageB(1, 0); stageB(1, 1); kB = 128;

    v4f acc[8][NFC] = {};
    const int nt = K >> 6;

    asm volatile("s_waitcnt vmcnt(%0)" :: "i"(2 * NLB) : "memory");
    __builtin_amdgcn_s_barrier();

    for (int tt = 0; tt < nt; ++tt) {
        const int bi = tt & 1;
        const unsigned short* Ah = &Ab[bi][wmh][0];
        const unsigned short* Bh = &Bb[bi][bhalf][bbase * 64];
        v8s af[4][2], bf[NFC][2];

        #pragma unroll
        for (int fr = 0; fr < 4; ++fr) {
            af[fr][0] = *(const v8s*)(Ah + fr * 1024 + ak0);
            af[fr][1] = *(const v8s*)(Ah + fr * 1024 + ak1);
        }
        #pragma unroll
        for (int fc = 0; fc < FCH; ++fc) {
            bf[fc][0] = *(const v8s*)(Bh + fc * 1024 + ak0);
            bf[fc][1] = *(const v8s*)(Bh + fc * 1024 + ak1);
        }
        if (tt + 1 < nt) stageA(bi ^ 1, 0);
        __builtin_amdgcn_s_barrier();
        asm volatile("s_waitcnt lgkmcnt(0)" ::: "memory");
        __builtin_amdgcn_s_setprio(1);
        #pragma unroll
        for (int fr = 0; fr < 4; ++fr)
            #pragma unroll
            for (int fc = 0; fc < FCH; ++fc) {
                acc[fr][fc] = __builtin_amdgcn_mfma_f32_16x16x32_bf16(bf[fc][0], af[fr][0], acc[fr][fc], 0, 0, 0);
                acc[fr][fc] = __builtin_amdgcn_mfma_f32_16x16x32_bf16(bf[fc][1], af[fr][1], acc[fr][fc], 0, 0, 0);
            }
        __builtin_amdgcn_s_setprio(0);
        __builtin_amdgcn_s_barrier();

        #pragma unroll
        for (int fc = FCH; fc < NFC; ++fc) {
            bf[fc][0] = *(const v8s*)(Bh + fc * 1024 + ak0);
            bf[fc][1] = *(const v8s*)(Bh + fc * 1024 + ak1);
        }
        if (tt + 1 < nt) stageA(bi ^ 1, 1);
        kA += 64;
        __builtin_amdgcn_s_barrier();
        asm volatile("s_waitcnt lgkmcnt(0)" ::: "memory");
        __builtin_amdgcn_s_setprio(1);
        #pragma unroll
        for (int fr = 0; fr < 4; ++fr)
            #pragma unroll
            for (int fc = FCH; fc < NFC; ++fc) {
                acc[fr][fc] = __builtin_amdgcn_mfma_f32_16x16x32_bf16(bf[fc][0], af[fr][0], acc[fr][fc], 0, 0, 0);
                acc[fr][fc] = __builtin_amdgcn_mfma_f32_16x16x32_bf16(bf[fc][1], af[fr][1], acc[fr][fc], 0, 0, 0);
            }
        __builtin_amdgcn_s_setprio(0);
        __builtin_amdgcn_s_barrier();

        #pragma unroll
        for (int fr = 0; fr < 4; ++fr) {
            af[fr][0] = *(const v8s*)(Ah + (fr + 4) * 1024 + ak0);
            af[fr][1] = *(const v8s*)(Ah + (fr + 4) * 1024 + ak1);
        }
        if (tt + 2 < nt) stageB(bi, 0);
        __builtin_amdgcn_s_barrier();
        asm volatile("s_waitcnt lgkmcnt(0)" ::: "memory");
        __builtin_amdgcn_s_setprio(1);
        #pragma unroll
        for (int fr = 0; fr < 4; ++fr)
            #pragma unroll
            for (int fc = 0; fc < FCH; ++fc) {
                acc[fr + 4][fc] = __builtin_amdgcn_mfma_f32_16x16x32_bf16(bf[fc][0], af[fr][0], acc[fr + 4][fc], 0, 0, 0);
                acc[fr + 4][fc] = __builtin_amdgcn_mfma_f32_16x16x32_bf16(bf[fc][1], af[fr][1], acc[fr + 4][fc], 0, 0, 0);
            }
        __builtin_amdgcn_s_setprio(0);
        __builtin_amdgcn_s_barrier();

        if (tt + 2 < nt) stageB(bi, 1);
        kB += 64;
        if (tt + 2 < nt)
            asm volatile("s_waitcnt vmcnt(%0)" :: "i"(2 * NLB) : "memory");
        else if (tt + 1 < nt)
            asm volatile("s_waitcnt vmcnt(0)" ::: "memory");
        __builtin_amdgcn_s_barrier();
        __builtin_amdgcn_s_setprio(1);
        #pragma unroll
        for (int fr = 0; fr < 4; ++fr)
            #pragma unroll
            for (int fc = FCH; fc < NFC; ++fc) {
                acc[fr + 4][fc] = __builtin_amdgcn_mfma_f32_16x16x32_bf16(bf[fc][0], af[fr][0], acc[fr + 4][fc], 0, 0, 0);
                acc[fr + 4][fc] = __builtin_amdgcn_mfma_f32_16x16x32_bf16(bf[fc][1], af[fr][1], acc[fr + 4][fc], 0, 0, 0);
            }
        __builtin_amdgcn_s_setprio(0);
        __builtin_amdgcn_s_barrier();
    }

    // epilogue: LN-fold + GELU
    #pragma unroll
    for (int fr = 0; fr < 8; ++fr) {
        long m = tileM + wmh * 128 + fr * 16 + l16;
        float s1, s2;
        if (SM == 0) {
            float2 st = *(const float2*)&stats[m * 2];
            s1 = st.x; s2 = st.y;
        } else {
            float4 q0 = *(const float4*)&stats[m * 8];
            float4 q1 = *(const float4*)&stats[m * 8 + 4];
            s1 = q0.x + q0.z + q1.x + q1.z;
            s2 = q0.y + q0.w + q1.y + q1.w;
        }
        float mu = s1 * (1.0f / 512.0f);
        float rinv = 1.0f / sqrtf(s2 * (1.0f / 512.0f) - mu * mu + 1e-5f);
        float rmu = rinv * mu;
        #pragma unroll
        for (int fc = 0; fc < NFC; ++fc) {
            long n0 = tileN + wn * (BN / 4) + fc * 16 + quad * 4;
            float4 c14 = *(const float4*)&c1[n0];
            float4 c24 = *(const float4*)&c2[n0];
            const float* c1p = (const float*)&c14;
            const float* c2p = (const float*)&c24;
            unsigned short pk[4];
            #pragma unroll
            for (int r = 0; r < 4; ++r)
                pk[r] = f2bf(fast_gelu(rinv * acc[fr][fc][r] - rmu * c1p[r] + c2p[r]));
            *(ushort4*)&Cout[m * ldc + n0] = *(ushort4*)pk;
        }
    }
}

// ------- w2 GEMM: 8-phase BM=256 BN=128, residual + x write + row-stat partials -------
__global__ __launch_bounds__(512, 1) void gemm_w2(
        const unsigned short* __restrict__ A,      // Hb [16384][1024]
        const unsigned short* __restrict__ BT,     // w2T [512][1024]
        const float* __restrict__ bias,            // b2 [512]
        unsigned short* __restrict__ x,            // residual in/out [16384][512]
        float* __restrict__ rowpart) {             // [16384][4][2]
    constexpr int BN = 128, NFC = 2, FCH = 1, NLB = 1, BH = 64;
    constexpr int lda = 1024, ldb = 1024, K = 1024;
    __shared__ unsigned short Ab[2][2][128 * 64] __attribute__((aligned(16)));
    __shared__ unsigned short Bb[2][2][BH * 64] __attribute__((aligned(16)));
    const int t = threadIdx.x;
    const int lane = t & 63, w = t >> 6;
    const int quad = lane >> 4, l16 = lane & 15;
    const int wmh = w >> 2;
    const int wn  = w & 3;
    const int bhalf = wn >> 1, bbase = (wn & 1) * (BN / 4);
    const long tileM = (long)blockIdx.x * 256;
    const int yb = blockIdx.y;
    const long tileN = (long)yb * BN;

    const int rl = lane >> 3;
    const int cl = ((lane & 7) ^ rl) * 8;

    const unsigned short* pa[2][2];
    #pragma unroll
    for (int h = 0; h < 2; ++h)
        #pragma unroll
        for (int q = 0; q < 2; ++q)
            pa[h][q] = A + (tileM + h * 128 + w * 16 + q * 8 + rl) * (size_t)lda + cl;
    const unsigned short* pb[2];
    #pragma unroll
    for (int h = 0; h < 2; ++h)
        pb[h] = BT + (tileN + h * BH + w * 8 + rl) * (size_t)ldb + cl;
    int kA = 0, kB = 0;

    auto stageA = [&](int buf, int h) {
        glds16(pa[h][0] + kA, &Ab[buf][h][(w * 2 + 0) * 512]);
        glds16(pa[h][1] + kA, &Ab[buf][h][(w * 2 + 1) * 512]);
    };
    auto stageB = [&](int buf, int h) {
        glds16(pb[h] + kB, &Bb[buf][h][w * 512]);
    };

    const int xl = l16 & 7;
    const int ak0 = l16 * 64 + (((quad    ) ^ xl) * 8);
    const int ak1 = l16 * 64 + (((quad + 4) ^ xl) * 8);

    stageA(0, 0); stageA(0, 1); kA = 64;
    stageB(0, 0); stageB(0, 1); kB = 64;
    stageB(1, 0); stageB(1, 1); kB = 128;

    v4f acc[8][NFC] = {};
    const int nt = K >> 6;

    asm volatile("s_waitcnt vmcnt(%0)" :: "i"(2 * NLB) : "memory");
    __builtin_amdgcn_s_barrier();

    for (int tt = 0; tt < nt; ++tt) {
        const int bi = tt & 1;
        const unsigned short* Ah = &Ab[bi][wmh][0];
        const unsigned short* Bh = &Bb[bi][bhalf][bbase * 64];
        v8s af[4][2], bf[NFC][2];

        #pragma unroll
        for (int fr = 0; fr < 4; ++fr) {
            af[fr][0] = *(const v8s*)(Ah + fr * 1024 + ak0);
            af[fr][1] = *(const v8s*)(Ah + fr * 1024 + ak1);
        }
        #pragma unroll
        for (int fc = 0; fc < FCH; ++fc) {
            bf[fc][0] = *(const v8s*)(Bh + fc * 1024 + ak0);
            bf[fc][1] = *(const v8s*)(Bh + fc * 1024 + ak1);
        }
        if (tt + 1 < nt) stageA(bi ^ 1, 0);
        __builtin_amdgcn_s_barrier();
        asm volatile("s_waitcnt lgkmcnt(0)" ::: "memory");
        __builtin_amdgcn_s_setprio(1);
        #pragma unroll
        for (int fr = 0; fr < 4; ++fr)
            #pragma unroll
            for (int fc = 0; fc < FCH; ++fc) {
                acc[fr][fc] = __builtin_amdgcn_mfma_f32_16x16x32_bf16(bf[fc][0], af[fr][0], acc[fr][fc], 0, 0, 0);
                acc[fr][fc] = __builtin_amdgcn_mfma_f32_16x16x32_bf16(bf[fc][1], af[fr][1], acc[fr][fc], 0, 0, 0);
            }
        __builtin_amdgcn_s_setprio(0);
        __builtin_amdgcn_s_barrier();

        #pragma unroll
        for (int fc = FCH; fc < NFC; ++fc) {
            bf[fc][0] = *(const v8s*)(Bh + fc * 1024 + ak0);
            bf[fc][1] = *(const v8s*)(Bh + fc * 1024 + ak1);
        }
        if (tt + 1 < nt) stageA(bi ^ 1, 1);
        kA += 64;
        __builtin_amdgcn_s_barrier();
        asm volatile("s_waitcnt lgkmcnt(0)" ::: "memory");
        __builtin_amdgcn_s_setprio(1);
        #pragma unroll
        for (int fr = 0; fr < 4; ++fr)
            #pragma unroll
            for (int fc = FCH; fc < NFC; ++fc) {
                acc[fr][fc] = __builtin_amdgcn_mfma_f32_16x16x32_bf16(bf[fc][0], af[fr][0], acc[fr][fc], 0, 0, 0);
                acc[fr][fc] = __builtin_amdgcn_mfma_f32_16x16x32_bf16(bf[fc][1], af[fr][1], acc[fr][fc], 0, 0, 0);
            }
        __builtin_amdgcn_s_setprio(0);
        __builtin_amdgcn_s_barrier();

        #pragma unroll
        for (int fr = 0; fr < 4; ++fr) {
            af[fr][0] = *(const v8s*)(Ah + (fr + 4) * 1024 + ak0);
            af[fr][1] = *(const v8s*)(Ah + (fr + 4) * 1024 + ak1);
        }
        if (tt + 2 < nt) stageB(bi, 0);
        __builtin_amdgcn_s_barrier();
        asm volatile("s_waitcnt lgkmcnt(0)" ::: "memory");
        __builtin_amdgcn_s_setprio(1);
        #pragma unroll
        for (int fr = 0; fr < 4; ++fr)
            #pragma unroll
            for (int fc = 0; fc < FCH; ++fc) {
                acc[fr + 4][fc] = __builtin_amdgcn_mfma_f32_16x16x32_bf16(bf[fc][0], af[fr][0], acc[fr + 4][fc], 0, 0, 0);
                acc[fr + 4][fc] = __builtin_amdgcn_mfma_f32_16x16x32_bf16(bf[fc][1], af[fr][1], acc[fr + 4][fc], 0, 0, 0);
            }
        __builtin_amdgcn_s_setprio(0);
        __builtin_amdgcn_s_barrier();

        if (tt + 2 < nt) stageB(bi, 1);
        kB += 64;
        if (tt + 2 < nt)
            asm volatile("s_waitcnt vmcnt(%0)" :: "i"(2 * NLB) : "memory");
        else if (tt + 1 < nt)
            asm volatile("s_waitcnt vmcnt(0)" ::: "memory");
        __builtin_amdgcn_s_barrier();
        __builtin_amdgcn_s_setprio(1);
        #pragma unroll
        for (int fr = 0; fr < 4; ++fr)
            #pragma unroll
            for (int fc = FCH; fc < NFC; ++fc) {
                acc[fr + 4][fc] = __builtin_amdgcn_mfma_f32_16x16x32_bf16(bf[fc][0], af[fr][0], acc[fr + 4][fc], 0, 0, 0);
                acc[fr + 4][fc] = __builtin_amdgcn_mfma_f32_16x16x32_bf16(bf[fc][1], af[fr][1], acc[fr + 4][fc], 0, 0, 0);
            }
        __builtin_amdgcn_s_setprio(0);
        __builtin_amdgcn_s_barrier();
    }

    // epilogue: residual add, x write, per-row partial stats over this block's 128 cols
    float p1[8], p2[8];
    #pragma unroll
    for (int fr = 0; fr < 8; ++fr) { p1[fr] = 0.f; p2[fr] = 0.f; }
    #pragma unroll
    for (int fr = 0; fr < 8; ++fr) {
        long m = tileM + wmh * 128 + fr * 16 + l16;
        #pragma unroll
        for (int fc = 0; fc < NFC; ++fc) {
            long n0 = tileN + wn * (BN / 4) + fc * 16 + quad * 4;
            float4 bi4 = *(const float4*)&bias[n0 - tileN + yb * BN];   // bias is global-n indexed
            const float* bip = (const float*)&bi4;
            ushort4 xr4 = *(const ushort4*)&x[m * 512 + n0];
            const unsigned short* xp = (const unsigned short*)&xr4;
            unsigned short pk[4];
            #pragma unroll
            for (int r = 0; r < 4; ++r) {
                float v = acc[fr][fc][r] + bip[r] + bf2f(xp[r]);
                p1[fr] += v; p2[fr] += v * v;
                pk[r] = f2bf(v);
            }
            *(ushort4*)&x[m * 512 + n0] = *(ushort4*)pk;
        }
    }
    #pragma unroll
    for (int fr = 0; fr < 8; ++fr) {
        p1[fr] += __shfl_xor(p1[fr], 16); p1[fr] += __shfl_xor(p1[fr], 32);
        p2[fr] += __shfl_xor(p2[fr], 16); p2[fr] += __shfl_xor(p2[fr], 32);
    }
    float* red = (float*)&Ab[0][0][0];          // reuse LDS: [256][4] s1 then s2
    if (quad == 0) {
        #pragma unroll
        for (int fr = 0; fr < 8; ++fr) {
            int r = wmh * 128 + fr * 16 + l16;
            red[r * 4 + wn] = p1[fr];
            red[1024 + r * 4 + wn] = p2[fr];
        }
    }
    __syncthreads();
    if (t < 256) {
        int r = t;
        float s1 = red[r * 4] + red[r * 4 + 1] + red[r * 4 + 2] + red[r * 4 + 3];
        float s2 = red[1024 + r * 4] + red[1024 + r * 4 + 1] + red[1024 + r * 4 + 2] + red[1024 + r * 4 + 3];
        long m = tileM + r;
        rowpart[m * 8 + yb * 2]     = s1;
        rowpart[m * 8 + yb * 2 + 1] = s2;
    }
}

// ------- fused tanh-GEMM + class-GEMM, reads raw x, role-LN folded -------
__global__ __launch_bounds__(256) void tanh_class_kernel(
        const unsigned short* __restrict__ A,       // x final
        const unsigned short* __restrict__ WT,      // role-g-folded wabcT
        const unsigned short* __restrict__ cls,
        const float* __restrict__ rowpart,          // rowpart2 [m][4][2]
        const float* __restrict__ c1a, const float* __restrict__ c2a,
        unsigned short* __restrict__ uu) {
    __shared__ unsigned short As[128][40] __attribute__((aligned(16)));
    __shared__ unsigned short Bs[64][40] __attribute__((aligned(16)));
    __shared__ unsigned short P[128 * 72] __attribute__((aligned(16)));
    const int t = threadIdx.x;
    const int lane = t & 63, wave = t >> 6;
    const int quad = lane >> 4, l16 = lane & 15;
    const int wm = (wave >> 1) * 64, wn = (wave & 1) * 32;
    const long tileM = (long)blockIdx.x * 128;
    const int g = blockIdx.y;
    const int arow = t >> 2, acol = (t & 3) * 8;

    const unsigned short* BT = WT + g * 32768;
    v8s cf[2][2];
    #pragma unroll
    for (int ks = 0; ks < 2; ++ks)
        #pragma unroll
        for (int j = 0; j < 2; ++j)
            cf[ks][j] = *(const v8s*)&cls[g * 4096 + (wn + j * 16 + l16) * 64 + ks * 32 + quad * 8];

    const unsigned short* gA0 = A + (tileM + arow) * 512 + acol;
    const unsigned short* gA1 = gA0 + 64 * 512;
    const unsigned short* gB0 = BT + arow * 512 + acol;

    v4f acc[4][2] = {};
    uint4 a0, a1, b0;
    a0 = *(const uint4*)gA0; a1 = *(const uint4*)gA1; gA0 += 32; gA1 += 32;
    b0 = *(const uint4*)gB0; gB0 += 32;
    *(uint4*)&As[arow][acol] = a0;
    *(uint4*)&As[arow + 64][acol] = a1;
    *(uint4*)&Bs[arow][acol] = b0;

    for (int kk = 0; kk < 16; ++kk) {
        __syncthreads();
        const bool more = kk < 15;
        if (more) {
            a0 = *(const uint4*)gA0; a1 = *(const uint4*)gA1; gA0 += 32; gA1 += 32;
            b0 = *(const uint4*)gB0; gB0 += 32;
        }
        v8s af[4], bfr[2];
        #pragma unroll
        for (int i = 0; i < 4; ++i) af[i] = *(const v8s*)&As[wm + i * 16 + l16][quad * 8];
        #pragma unroll
        for (int j = 0; j < 2; ++j) bfr[j] = *(const v8s*)&Bs[wn + j * 16 + l16][quad * 8];
        #pragma unroll
        for (int i = 0; i < 4; ++i)
            #pragma unroll
            for (int j = 0; j < 2; ++j)
                acc[i][j] = __builtin_amdgcn_mfma_f32_16x16x32_bf16(bfr[j], af[i], acc[i][j], 0, 0, 0);
        __syncthreads();
        if (more) {
            *(uint4*)&As[arow][acol] = a0;
            *(uint4*)&As[arow + 64][acol] = a1;
            *(uint4*)&Bs[arow][acol] = b0;
        }
    }

    // role-LN fold + tanh -> P
    #pragma unroll
    for (int i = 0; i < 4; ++i) {
        int m = wm + i * 16 + l16;
        long gm = tileM + m;
        float4 q0 = *(const float4*)&rowpart[gm * 8];
        float4 q1 = *(const float4*)&rowpart[gm * 8 + 4];
        float s1 = q0.x + q0.z + q1.x + q1.z;
        float s2 = q0.y + q0.w + q1.y + q1.w;
        float mu = s1 * (1.0f / 512.0f);
        float rinv = 1.0f / sqrtf(s2 * (1.0f / 512.0f) - mu * mu + 1e-5f);
        float rmu = rinv * mu;
        #pragma unroll
        for (int j = 0; j < 2; ++j) {
            int n0 = wn + j * 16 + quad * 4;
            float4 c14 = *(const float4*)&c1a[g * 64 + n0];
            float4 c24 = *(const float4*)&c2a[g * 64 + n0];
            const float* c1p = (const float*)&c14;
            const float* c2p = (const float*)&c24;
            unsigned short pk[4];
            #pragma unroll
            for (int r = 0; r < 4; ++r)
                pk[r] = f2bf(fast_tanh(rinv * acc[i][j][r] - rmu * c1p[r] + c2p[r]));
            *(ushort4*)&P[m * 72 + n0] = *(ushort4*)pk;
        }
    }
    __syncthreads();

    v4f acc2[4][2] = {};
    #pragma unroll
    for (int ks = 0; ks < 2; ++ks) {
        v8s paf[4];
        #pragma unroll
        for (int i = 0; i < 4; ++i)
            paf[i] = *(const v8s*)&P[(wm + i * 16 + l16) * 72 + ks * 32 + quad * 8];
        #pragma unroll
        for (int i = 0; i < 4; ++i)
            #pragma unroll
            for (int j = 0; j < 2; ++j)
                acc2[i][j] = __builtin_amdgcn_mfma_f32_16x16x32_bf16(cf[ks][j], paf[i], acc2[i][j], 0, 0, 0);
    }

    #pragma unroll
    for (int i = 0; i < 4; ++i) {
        long m = tileM + wm + i * 16 + l16;
        #pragma unroll
        for (int j = 0; j < 2; ++j) {
            int c0 = wn + j * 16 + quad * 4;
            unsigned short pk[4];
            #pragma unroll
            for (int r = 0; r < 4; ++r) pk[r] = f2bf(acc2[i][j][r]);
            *(ushort4*)&uu[m * 192 + g * 64 + c0] = *(ushort4*)pk;
        }
    }
}

// ------- exact ordered-triplet scan pass 1 -------
__global__ __launch_bounds__(64) void scan_part_kernel(const unsigned short* __restrict__ u,
                                                       float* __restrict__ part) {
    int b = blockIdx.x, seg = blockIdx.y;
    int c = threadIdx.x;
    int l0 = seg * 32;
    int l1 = l0 + 32; if (l1 > 2047) l1 = 2047;
    float sA = 0.f, sB = 0.f, sC = 0.f, T = 0.f, M = 0.f, U = 0.f;
    const unsigned short* base = u + ((size_t)b * LSEQ + l0) * 192 + c;
    for (int l = l0; l < l1; ++l) {
        float ua = bf2f(base[0]), ub = bf2f(base[64]), uc = bf2f(base[128]);
        base += 192;
        U += uc * T;
        M += uc * sB;
        T += ub * sA;
        sA += ua; sB += ub; sC += uc;
    }
    float* p = part + ((size_t)(b * 64 + seg)) * 384 + c;
    p[0] = sA; p[64] = sB; p[128] = sC; p[192] = T; p[256] = M; p[320] = U;
}

// ------- merged: segment combine + final LN + Wq GEMV -------
__global__ __launch_bounds__(64) void combine_final_kernel(const float* __restrict__ part,
        const unsigned short* __restrict__ x,
        const float* __restrict__ qw, const float* __restrict__ qb,
        const float* __restrict__ Wq, const float* __restrict__ bq,
        float* __restrict__ out, float inv_denom) {
    int b = blockIdx.x;
    int c = threadIdx.x;
    const float* p = part + (size_t)b * 64 * 384 + c;
    float A = p[0], B = p[64], Tt = p[192], Mt = p[256], Ut = p[320];
    for (int seg = 1; seg < 64; ++seg) {
        const float* q2 = p + seg * 384;
        float a2 = q2[0], b2 = q2[64], c2 = q2[128], t2 = q2[192], m2 = q2[256], u2 = q2[320];
        float Un = Ut + u2 + c2 * Tt + A * m2;
        float Tn = Tt + t2 + A * b2;
        float Mn = Mt + m2 + B * c2;
        A += a2; B += b2;
        Ut = Un; Tt = Tn; Mt = Mn;
    }
    __shared__ float q[512];
    __shared__ float mv[2];
    const unsigned short* xr = x + ((size_t)b * LSEQ + (LSEQ - 1)) * 512;
    float s1 = 0.f, s2 = 0.f;
    for (int i = c; i < 512; i += 64) { float v = bf2f(xr[i]); q[i] = v; s1 += v; s2 += v * v; }
    #pragma unroll
    for (int o = 32; o > 0; o >>= 1) { s1 += __shfl_down(s1, o); s2 += __shfl_down(s2, o); }
    if (c == 0) {
        float m = s1 * (1.0f / 512.0f);
        float var = s2 * (1.0f / 512.0f) - m * m;
        mv[0] = m; mv[1] = 1.0f / sqrtf(var + 1e-5f);
    }
    __syncthreads();
    float m = mv[0], r = mv[1];
    for (int i = c; i < 512; i += 64) q[i] = (q[i] - m) * r * qw[i] + qb[i];
    __syncthreads();
    float acc = 0.f;
    for (int d = 0; d < 512; ++d) acc += q[d] * Wq[d * 64 + c];
    out[b * 64 + c] = Ut * inv_denom + acc + bq[c];
}

extern "C" void kernel_launch(void* const* d_in, const int* in_sizes, int n_in,
                              void* d_out, int out_size, void* d_ws, size_t ws_size,
                              hipStream_t stream) {
    const int*   token_ids   = (const int*)d_in[0];
    const float* tok_emb     = (const float*)d_in[1];
    const float* pos_emb     = (const float*)d_in[2];
    const float* stem_ln_w   = (const float*)d_in[3];
    const float* stem_ln_b   = (const float*)d_in[4];
    const float* stem_w1     = (const float*)d_in[5];
    const float* stem_b1     = (const float*)d_in[6];
    const float* stem_w2     = (const float*)d_in[7];
    const float* stem_b2     = (const float*)d_in[8];
    const float* role_ln_w   = (const float*)d_in[9];
    const float* role_ln_b   = (const float*)d_in[10];
    const float* Wa          = (const float*)d_in[11];
    const float* Wb          = (const float*)d_in[12];
    const float* Wc          = (const float*)d_in[13];
    const float* class_a     = (const float*)d_in[14];
    const float* class_b     = (const float*)d_in[15];
    const float* class_c     = (const float*)d_in[16];
    const float* query_ln_w  = (const float*)d_in[17];
    const float* query_ln_b  = (const float*)d_in[18];
    const float* Wq          = (const float*)d_in[19];
    const float* bq          = (const float*)d_in[20];
    float* out = (float*)d_out;

    char* wsb = (char*)d_ws;
    unsigned short* x    = (unsigned short*)(wsb);              // 16,777,216
    unsigned short* Hb   = (unsigned short*)(wsb + 16777216);   // 33,554,432
    unsigned short* uu   = (unsigned short*)(wsb + 50331648);   // 6,291,456
    float* part          = (float*)(wsb + 56623104);            // 786,432
    unsigned short* w1T  = (unsigned short*)(wsb + 57409536);   // 2,097,152 (g-folded)
    unsigned short* w2T  = (unsigned short*)(wsb + 59506688);   // 2,097,152
    unsigned short* wabcT= (unsigned short*)(wsb + 61603840);   // 196,608 (role-g-folded)
    unsigned short* clsb = (unsigned short*)(wsb + 61800448);   // 24,576
    float* rowstat0      = (float*)(wsb + 61825024);            // 131,072
    float* rowpart1      = (float*)(wsb + 61956096);            // 524,288
    float* rowpart2      = (float*)(wsb + 62480384);            // 524,288
    float* c1buf         = (float*)(wsb + 63004672);            // 8,192
    float* c2buf         = (float*)(wsb + 63012864);            // 8,192
    float* c1a           = (float*)(wsb + 63021056);            // 768
    float* c2a           = (float*)(wsb + 63021824);            // 768

    setup_kernel<<<6252, 256, 0, stream>>>(token_ids, tok_emb, pos_emb,
        stem_ln_w, stem_ln_b, role_ln_w, role_ln_b, stem_b1,
        x, rowstat0,
        stem_w1, stem_w2, Wa, Wb, Wc, class_a, class_b, class_c,
        w1T, w2T, wabcT, clsb, c1buf, c2buf, c1a, c2a);

    // layer 0
    gemm_w1<0><<<dim3(64, 4), 512, 0, stream>>>(
        x, w1T, c1buf, c2buf, rowstat0, Hb);
    gemm_w2<<<dim3(64, 4), 512, 0, stream>>>(
        Hb, w2T, stem_b2, x, rowpart1);
    // layer 1
    gemm_w1<1><<<dim3(64, 4), 512, 0, stream>>>(
        x, w1T + 524288, c1buf + 1024, c2buf + 1024, rowpart1, Hb);
    gemm_w2<<<dim3(64, 4), 512, 0, stream>>>(
        Hb, w2T + 524288, stem_b2 + 512, x, rowpart2);

    tanh_class_kernel<<<dim3(128, 3), 256, 0, stream>>>(x, wabcT, clsb,
                                                        rowpart2, c1a, c2a, uu);

    scan_part_kernel<<<dim3(NB, 64), 64, 0, stream>>>(uu, part);

    float inv_denom = (float)(6.0 / (2047.0 * 2046.0 * 2045.0));
    combine_final_kernel<<<NB, 64, 0, stream>>>(part, x, query_ln_w, query_ln_b,
                                                Wq, bq, out, inv_denom);
}

// Round 8
// 326.630 us; speedup vs baseline: 1.0771x; 1.0610x over previous
//
#include <hip/hip_runtime.h>

#define NROWS 16384   // B*L
#define LSEQ  2048
#define NB    8

typedef short v8s __attribute__((ext_vector_type(8)));
typedef float v4f __attribute__((ext_vector_type(4)));

__device__ __forceinline__ unsigned short f2bf(float f) {
    unsigned int u = __float_as_uint(f);
    return (unsigned short)((u + 0x7fffu + ((u >> 16) & 1u)) >> 16);
}
__device__ __forceinline__ float bf2f(unsigned short u) {
    return __uint_as_float(((unsigned int)u) << 16);
}

// async global->LDS, 16B per lane; LDS dest is wave-uniform base + lane*16
__device__ __forceinline__ void glds16(const void* g, void* l) {
    __builtin_amdgcn_global_load_lds(
        (__attribute__((address_space(1))) void*)g,
        (__attribute__((address_space(3))) void*)l,
        16, 0, 0);
}

// fast exact-GELU: Abramowitz-Stegun 5-term erf, |err|<1.5e-7
__device__ __forceinline__ float fast_gelu(float v) {
    float z = fabsf(v) * 0.70710678118654752f;
    float t = __builtin_amdgcn_rcpf(1.0f + 0.3275911f * z);
    float poly = t * (0.254829592f + t * (-0.284496736f + t * (1.421413741f +
                 t * (-1.453152027f + t * 1.061405429f))));
    float erfz = 1.0f - poly * __expf(-z * z);
    float er = copysignf(erfz, v);
    return 0.5f * v * (1.0f + er);
}
__device__ __forceinline__ float fast_tanh(float y) {
    float e = __expf(2.0f * y);
    return (e - 1.0f) * __builtin_amdgcn_rcpf(e + 1.0f);
}

// XCD row-swizzle: block b (of 4096, 4 rows each) -> rows of 128-row tile T with
// T%8 == b%8, so the producer's XCD matches the GEMM reader's XCD.
__device__ __forceinline__ long swizzled_row(int b, int wave) {
    int T = (b & 7) + (((b >> 3) & 15) << 3);   // 0..127, T%8 == b%8
    int chunk = b >> 7;                          // 0..31
    return (long)T * 128 + chunk * 4 + wave;
}

// ------- merged setup:
//   blocks 0..4095     : embed (XCD-swizzled) -> x + rowstat0 (s1,s2)
//   blocks 4096..6239  : weight transposes; gamma FOLDED into w1T / wabcT
//   blocks 6240..6242  : class bf16 converts
//   blocks 6243..6306  : w1 LN colsum constants c1,c2 (parallel: 64 blocks, k-split)
//   blocks 6307..6309  : wa/wb/wc LN colsum constants c1a,c2a (3 blocks, k-split)
__global__ __launch_bounds__(256) void setup_kernel(
        const int* __restrict__ ids,
        const float* __restrict__ tok, const float* __restrict__ pos,
        const float* __restrict__ g0, const float* __restrict__ b0,   // stem_ln_w/b [2][512]
        const float* __restrict__ rolew, const float* __restrict__ roleb,
        const float* __restrict__ b1all,                              // stem_b1 [2][1024]
        unsigned short* __restrict__ x, float* __restrict__ rowstat0,
        const float* __restrict__ w1, const float* __restrict__ w2,
        const float* __restrict__ wa, const float* __restrict__ wb, const float* __restrict__ wc,
        const float* __restrict__ ca, const float* __restrict__ cb, const float* __restrict__ cc,
        unsigned short* __restrict__ w1T, unsigned short* __restrict__ w2T,
        unsigned short* __restrict__ wabcT, unsigned short* __restrict__ clsb,
        float* __restrict__ c1buf, float* __restrict__ c2buf,
        float* __restrict__ c1a, float* __restrict__ c2a) {
    int blk = blockIdx.x;
    int t = threadIdx.x;
    if (blk < 4096) {
        int wave = t >> 6, lane = t & 63;
        long row = swizzled_row(blk, wave);
        int l = (int)(row & (LSEQ - 1));
        int id = ids[row];
        int d = lane * 8;
        float4 t0 = *(const float4*)(tok + (size_t)id * 512 + d);
        float4 t1 = *(const float4*)(tok + (size_t)id * 512 + d + 4);
        float4 p0 = *(const float4*)(pos + (size_t)l * 512 + d);
        float4 p1 = *(const float4*)(pos + (size_t)l * 512 + d + 4);
        float a[8] = {t0.x + p0.x, t0.y + p0.y, t0.z + p0.z, t0.w + p0.w,
                      t1.x + p1.x, t1.y + p1.y, t1.z + p1.z, t1.w + p1.w};
        unsigned int xp[4];
        #pragma unroll
        for (int i = 0; i < 4; ++i)
            xp[i] = (unsigned int)f2bf(a[2 * i]) | ((unsigned int)f2bf(a[2 * i + 1]) << 16);
        *(uint4*)(x + row * 512 + d) = *(uint4*)xp;
        float s = 0.f, s2 = 0.f;
        #pragma unroll
        for (int i = 0; i < 8; ++i) { s += a[i]; s2 += a[i] * a[i]; }
        #pragma unroll
        for (int o = 32; o > 0; o >>= 1) { s += __shfl_down(s, o); s2 += __shfl_down(s2, o); }
        if (lane == 0) {
            rowstat0[row * 2] = s;
            rowstat0[row * 2 + 1] = s2;
        }
    } else if (blk < 6240) {
        int id = blk - 4096;
        int tx = t & 31, ty = t >> 5;
        const float* in; unsigned short* out; int R, C, bx, by, ldo;
        const float* gfold = nullptr;    // row-index (k) gamma fold
        if (id < 1024) {
            int l = id >> 9, r = id & 511;
            in = w1 + l * 524288; out = w1T + l * 524288;
            R = 512; C = 1024; bx = r & 31; by = r >> 5; ldo = 512;
            gfold = g0 + l * 512;
        } else if (id < 2048) {
            int l = (id - 1024) >> 9, r = (id - 1024) & 511;
            in = w2 + l * 524288; out = w2T + l * 524288;
            R = 1024; C = 512; bx = r & 15; by = r >> 4; ldo = 1024;
        } else {
            int g = (id - 2048) >> 5, r = (id - 2048) & 31;
            in = (g == 0) ? wa : (g == 1) ? wb : wc;
            out = wabcT + g * 32768;
            R = 512; C = 64; bx = r & 1; by = r >> 1; ldo = 512;
            gfold = rolew;
        }
        __shared__ unsigned short tile[32][33];
        int c0 = bx * 32, r0 = by * 32;
        for (int i = ty; i < 32; i += 8) {
            int r = r0 + i, c = c0 + tx;
            float v = (r < R && c < C) ? in[(size_t)r * C + c] : 0.f;
            if (gfold && r < R) v *= gfold[r];
            tile[i][tx] = f2bf(v);
        }
        __syncthreads();
        for (int i = ty; i < 32; i += 8) {
            int c = c0 + i, r = r0 + tx;
            if (r < R && c < C) out[(size_t)c * ldo + r] = tile[tx][i];
        }
    } else if (blk < 6243) {
        int g = blk - 6240;
        const float* src = (g == 0) ? ca : (g == 1) ? cb : cc;
        unsigned short* dst = clsb + g * 4096;
        for (int i = t; i < 4096; i += 256) dst[i] = f2bf(src[i]);
    } else if (blk < 6307) {
        // w1 colsums, parallel: 64 blocks = 2 layers x 32 n-chunks of 32.
        // threads: n_local = t&31, kq = t>>5 (8 k-chunks of 64)
        int idx = blk - 6243;
        int l = idx >> 5, nch = idx & 31;
        int n = nch * 32 + (t & 31);
        int kq = t >> 5;
        const float* W = w1 + l * 524288;
        const float* g = g0 + l * 512;
        const float* b = b0 + l * 512;
        float a1 = 0.f, a2 = 0.f;
        for (int k = kq * 64; k < kq * 64 + 64; ++k) {
            float w = W[(size_t)k * 1024 + n];
            a1 += g[k] * w;
            a2 += b[k] * w;
        }
        __shared__ float red1[8][32], red2[8][32];
        red1[kq][t & 31] = a1;
        red2[kq][t & 31] = a2;
        __syncthreads();
        if (t < 32) {
            float s1 = 0.f, s2 = 0.f;
            #pragma unroll
            for (int q = 0; q < 8; ++q) { s1 += red1[q][t]; s2 += red2[q][t]; }
            int nn = nch * 32 + t;
            c1buf[l * 1024 + nn] = s1;
            c2buf[l * 1024 + nn] = s2 + b1all[l * 1024 + nn];
        }
    } else {
        // abc colsums: 3 blocks, one per group; threads: n=t&63, kq=t>>6 (4x128)
        int gi = blk - 6307;
        const float* W = (gi == 0) ? wa : (gi == 1) ? wb : wc;
        int n = t & 63, kq = t >> 6;
        float a1 = 0.f, a2 = 0.f;
        for (int k = kq * 128; k < kq * 128 + 128; ++k) {
            float w = W[(size_t)k * 64 + n];
            a1 += rolew[k] * w;
            a2 += roleb[k] * w;
        }
        __shared__ float red1[4][64], red2[4][64];
        red1[kq][n] = a1;
        red2[kq][n] = a2;
        __syncthreads();
        if (t < 64) {
            float s1 = 0.f, s2 = 0.f;
            #pragma unroll
            for (int q = 0; q < 4; ++q) { s1 += red1[q][t]; s2 += red2[q][t]; }
            c1a[gi * 64 + t] = s1;
            c2a[gi * 64 + t] = s2;
        }
    }
}

// ------- w1 GEMM: 8-phase BM=256 BN=256, reads raw x, LN folded -------
// h = gelu( rinv*acc - rinv*mu*c1[n] + c2[n] )
// SM=0: stats = rowstat0[m][2] direct.  SM=1: stats = rowpart[m][4][2], sum 4.
template <int SM>
__global__ __launch_bounds__(512, 1) void gemm_w1(
        const unsigned short* __restrict__ A,      // x [16384][512]
        const unsigned short* __restrict__ BT,     // g-folded w1T [1024][512]
        const float* __restrict__ c1, const float* __restrict__ c2,
        const float* __restrict__ stats,
        unsigned short* __restrict__ Cout) {       // Hb [16384][1024]
    constexpr int BN = 256, NFC = 4, FCH = 2, NLB = 2, BH = 128;
    constexpr int lda = 512, ldb = 512, ldc = 1024, K = 512;
    __shared__ unsigned short Ab[2][2][128 * 64] __attribute__((aligned(16)));
    __shared__ unsigned short Bb[2][2][BH * 64] __attribute__((aligned(16)));
    const int t = threadIdx.x;
    const int lane = t & 63, w = t >> 6;
    const int quad = lane >> 4, l16 = lane & 15;
    const int wmh = w >> 2;
    const int wn  = w & 3;
    const int bhalf = wn >> 1, bbase = (wn & 1) * (BN / 4);
    const long tileM = (long)blockIdx.x * 256;
    const long tileN = (long)blockIdx.y * BN;

    const int rl = lane >> 3;
    const int cl = ((lane & 7) ^ rl) * 8;

    const unsigned short* pa[2][2];
    #pragma unroll
    for (int h = 0; h < 2; ++h)
        #pragma unroll
        for (int q = 0; q < 2; ++q)
            pa[h][q] = A + (tileM + h * 128 + w * 16 + q * 8 + rl) * (size_t)lda + cl;
    const unsigned short* pb[2][2];
    #pragma unroll
    for (int h = 0; h < 2; ++h)
        #pragma unroll
        for (int q = 0; q < 2; ++q)
            pb[h][q] = BT + (tileN + h * BH + w * 16 + q * 8 + rl) * (size_t)ldb + cl;
    int kA = 0, kB = 0;

    auto stageA = [&](int buf, int h) {
        glds16(pa[h][0] + kA, &Ab[buf][h][(w * 2 + 0) * 512]);
        glds16(pa[h][1] + kA, &Ab[buf][h][(w * 2 + 1) * 512]);
    };
    auto stageB = [&](int buf, int h) {
        glds16(pb[h][0] + kB, &Bb[buf][h][(w * 2 + 0) * 512]);
        glds16(pb[h][1] + kB, &Bb[buf][h][(w * 2 + 1) * 512]);
    };

    const int xl = l16 & 7;
    const int ak0 = l16 * 64 + (((quad    ) ^ xl) * 8);
    const int ak1 = l16 * 64 + (((quad + 4) ^ xl) * 8);

    stageA(0, 0); stageA(0, 1); kA = 64;
    stageB(0, 0); stageB(0, 1); kB = 64;
    stageB(1, 0); stageB(1, 1); kB = 128;

    v4f acc[8][NFC] = {};
    const int nt = K >> 6;

    asm volatile("s_waitcnt vmcnt(%0)" :: "i"(2 * NLB) : "memory");
    __builtin_amdgcn_s_barrier();

    for (int tt = 0; tt < nt; ++tt) {
        const int bi = tt & 1;
        const unsigned short* Ah = &Ab[bi][wmh][0];
        const unsigned short* Bh = &Bb[bi][bhalf][bbase * 64];
        v8s af[4][2], bf[NFC][2];

        #pragma unroll
        for (int fr = 0; fr < 4; ++fr) {
            af[fr][0] = *(const v8s*)(Ah + fr * 1024 + ak0);
            af[fr][1] = *(const v8s*)(Ah + fr * 1024 + ak1);
        }
        #pragma unroll
        for (int fc = 0; fc < FCH; ++fc) {
            bf[fc][0] = *(const v8s*)(Bh + fc * 1024 + ak0);
            bf[fc][1] = *(const v8s*)(Bh + fc * 1024 + ak1);
        }
        if (tt + 1 < nt) stageA(bi ^ 1, 0);
        __builtin_amdgcn_s_barrier();
        asm volatile("s_waitcnt lgkmcnt(0)" ::: "memory");
        __builtin_amdgcn_s_setprio(1);
        #pragma unroll
        for (int fr = 0; fr < 4; ++fr)
            #pragma unroll
            for (int fc = 0; fc < FCH; ++fc) {
                acc[fr][fc] = __builtin_amdgcn_mfma_f32_16x16x32_bf16(bf[fc][0], af[fr][0], acc[fr][fc], 0, 0, 0);
                acc[fr][fc] = __builtin_amdgcn_mfma_f32_16x16x32_bf16(bf[fc][1], af[fr][1], acc[fr][fc], 0, 0, 0);
            }
        __builtin_amdgcn_s_setprio(0);
        __builtin_amdgcn_s_barrier();

        #pragma unroll
        for (int fc = FCH; fc < NFC; ++fc) {
            bf[fc][0] = *(const v8s*)(Bh + fc * 1024 + ak0);
            bf[fc][1] = *(const v8s*)(Bh + fc * 1024 + ak1);
        }
        if (tt + 1 < nt) stageA(bi ^ 1, 1);
        kA += 64;
        __builtin_amdgcn_s_barrier();
        asm volatile("s_waitcnt lgkmcnt(0)" ::: "memory");
        __builtin_amdgcn_s_setprio(1);
        #pragma unroll
        for (int fr = 0; fr < 4; ++fr)
            #pragma unroll
            for (int fc = FCH; fc < NFC; ++fc) {
                acc[fr][fc] = __builtin_amdgcn_mfma_f32_16x16x32_bf16(bf[fc][0], af[fr][0], acc[fr][fc], 0, 0, 0);
                acc[fr][fc] = __builtin_amdgcn_mfma_f32_16x16x32_bf16(bf[fc][1], af[fr][1], acc[fr][fc], 0, 0, 0);
            }
        __builtin_amdgcn_s_setprio(0);
        __builtin_amdgcn_s_barrier();

        #pragma unroll
        for (int fr = 0; fr < 4; ++fr) {
            af[fr][0] = *(const v8s*)(Ah + (fr + 4) * 1024 + ak0);
            af[fr][1] = *(const v8s*)(Ah + (fr + 4) * 1024 + ak1);
        }
        if (tt + 2 < nt) stageB(bi, 0);
        __builtin_amdgcn_s_barrier();
        asm volatile("s_waitcnt lgkmcnt(0)" ::: "memory");
        __builtin_amdgcn_s_setprio(1);
        #pragma unroll
        for (int fr = 0; fr < 4; ++fr)
            #pragma unroll
            for (int fc = 0; fc < FCH; ++fc) {
                acc[fr + 4][fc] = __builtin_amdgcn_mfma_f32_16x16x32_bf16(bf[fc][0], af[fr][0], acc[fr + 4][fc], 0, 0, 0);
                acc[fr + 4][fc] = __builtin_amdgcn_mfma_f32_16x16x32_bf16(bf[fc][1], af[fr][1], acc[fr + 4][fc], 0, 0, 0);
            }
        __builtin_amdgcn_s_setprio(0);
        __builtin_amdgcn_s_barrier();

        if (tt + 2 < nt) stageB(bi, 1);
        kB += 64;
        if (tt + 2 < nt)
            asm volatile("s_waitcnt vmcnt(%0)" :: "i"(2 * NLB) : "memory");
        else if (tt + 1 < nt)
            asm volatile("s_waitcnt vmcnt(0)" ::: "memory");
        __builtin_amdgcn_s_barrier();
        __builtin_amdgcn_s_setprio(1);
        #pragma unroll
        for (int fr = 0; fr < 4; ++fr)
            #pragma unroll
            for (int fc = FCH; fc < NFC; ++fc) {
                acc[fr + 4][fc] = __builtin_amdgcn_mfma_f32_16x16x32_bf16(bf[fc][0], af[fr][0], acc[fr + 4][fc], 0, 0, 0);
                acc[fr + 4][fc] = __builtin_amdgcn_mfma_f32_16x16x32_bf16(bf[fc][1], af[fr][1], acc[fr + 4][fc], 0, 0, 0);
            }
        __builtin_amdgcn_s_setprio(0);
        __builtin_amdgcn_s_barrier();
    }

    // epilogue: LN-fold + GELU
    #pragma unroll
    for (int fr = 0; fr < 8; ++fr) {
        long m = tileM + wmh * 128 + fr * 16 + l16;
        float s1, s2;
        if (SM == 0) {
            float2 st = *(const float2*)&stats[m * 2];
            s1 = st.x; s2 = st.y;
        } else {
            float4 q0 = *(const float4*)&stats[m * 8];
            float4 q1 = *(const float4*)&stats[m * 8 + 4];
            s1 = q0.x + q0.z + q1.x + q1.z;
            s2 = q0.y + q0.w + q1.y + q1.w;
        }
        float mu = s1 * (1.0f / 512.0f);
        float rinv = 1.0f / sqrtf(s2 * (1.0f / 512.0f) - mu * mu + 1e-5f);
        float rmu = rinv * mu;
        #pragma unroll
        for (int fc = 0; fc < NFC; ++fc) {
            long n0 = tileN + wn * (BN / 4) + fc * 16 + quad * 4;
            float4 c14 = *(const float4*)&c1[n0];
            float4 c24 = *(const float4*)&c2[n0];
            const float* c1p = (const float*)&c14;
            const float* c2p = (const float*)&c24;
            unsigned short pk[4];
            #pragma unroll
            for (int r = 0; r < 4; ++r)
                pk[r] = f2bf(fast_gelu(rinv * acc[fr][fc][r] - rmu * c1p[r] + c2p[r]));
            *(ushort4*)&Cout[m * ldc + n0] = *(ushort4*)pk;
        }
    }
}

// ------- w2 GEMM: 8-phase BM=256 BN=128, residual + x write + row-stat partials -------
__global__ __launch_bounds__(512, 1) void gemm_w2(
        const unsigned short* __restrict__ A,      // Hb [16384][1024]
        const unsigned short* __restrict__ BT,     // w2T [512][1024]
        const float* __restrict__ bias,            // b2 [512]
        unsigned short* __restrict__ x,            // residual in/out [16384][512]
        float* __restrict__ rowpart) {             // [16384][4][2]
    constexpr int BN = 128, NFC = 2, FCH = 1, NLB = 1, BH = 64;
    constexpr int lda = 1024, ldb = 1024, K = 1024;
    __shared__ unsigned short Ab[2][2][128 * 64] __attribute__((aligned(16)));
    __shared__ unsigned short Bb[2][2][BH * 64] __attribute__((aligned(16)));
    const int t = threadIdx.x;
    const int lane = t & 63, w = t >> 6;
    const int quad = lane >> 4, l16 = lane & 15;
    const int wmh = w >> 2;
    const int wn  = w & 3;
    const int bhalf = wn >> 1, bbase = (wn & 1) * (BN / 4);
    const long tileM = (long)blockIdx.x * 256;
    const int yb = blockIdx.y;
    const long tileN = (long)yb * BN;

    const int rl = lane >> 3;
    const int cl = ((lane & 7) ^ rl) * 8;

    const unsigned short* pa[2][2];
    #pragma unroll
    for (int h = 0; h < 2; ++h)
        #pragma unroll
        for (int q = 0; q < 2; ++q)
            pa[h][q] = A + (tileM + h * 128 + w * 16 + q * 8 + rl) * (size_t)lda + cl;
    const unsigned short* pb[2];
    #pragma unroll
    for (int h = 0; h < 2; ++h)
        pb[h] = BT + (tileN + h * BH + w * 8 + rl) * (size_t)ldb + cl;
    int kA = 0, kB = 0;

    auto stageA = [&](int buf, int h) {
        glds16(pa[h][0] + kA, &Ab[buf][h][(w * 2 + 0) * 512]);
        glds16(pa[h][1] + kA, &Ab[buf][h][(w * 2 + 1) * 512]);
    };
    auto stageB = [&](int buf, int h) {
        glds16(pb[h] + kB, &Bb[buf][h][w * 512]);
    };

    const int xl = l16 & 7;
    const int ak0 = l16 * 64 + (((quad    ) ^ xl) * 8);
    const int ak1 = l16 * 64 + (((quad + 4) ^ xl) * 8);

    stageA(0, 0); stageA(0, 1); kA = 64;
    stageB(0, 0); stageB(0, 1); kB = 64;
    stageB(1, 0); stageB(1, 1); kB = 128;

    v4f acc[8][NFC] = {};
    const int nt = K >> 6;

    asm volatile("s_waitcnt vmcnt(%0)" :: "i"(2 * NLB) : "memory");
    __builtin_amdgcn_s_barrier();

    for (int tt = 0; tt < nt; ++tt) {
        const int bi = tt & 1;
        const unsigned short* Ah = &Ab[bi][wmh][0];
        const unsigned short* Bh = &Bb[bi][bhalf][bbase * 64];
        v8s af[4][2], bf[NFC][2];

        #pragma unroll
        for (int fr = 0; fr < 4; ++fr) {
            af[fr][0] = *(const v8s*)(Ah + fr * 1024 + ak0);
            af[fr][1] = *(const v8s*)(Ah + fr * 1024 + ak1);
        }
        #pragma unroll
        for (int fc = 0; fc < FCH; ++fc) {
            bf[fc][0] = *(const v8s*)(Bh + fc * 1024 + ak0);
            bf[fc][1] = *(const v8s*)(Bh + fc * 1024 + ak1);
        }
        if (tt + 1 < nt) stageA(bi ^ 1, 0);
        __builtin_amdgcn_s_barrier();
        asm volatile("s_waitcnt lgkmcnt(0)" ::: "memory");
        __builtin_amdgcn_s_setprio(1);
        #pragma unroll
        for (int fr = 0; fr < 4; ++fr)
            #pragma unroll
            for (int fc = 0; fc < FCH; ++fc) {
                acc[fr][fc] = __builtin_amdgcn_mfma_f32_16x16x32_bf16(bf[fc][0], af[fr][0], acc[fr][fc], 0, 0, 0);
                acc[fr][fc] = __builtin_amdgcn_mfma_f32_16x16x32_bf16(bf[fc][1], af[fr][1], acc[fr][fc], 0, 0, 0);
            }
        __builtin_amdgcn_s_setprio(0);
        __builtin_amdgcn_s_barrier();

        #pragma unroll
        for (int fc = FCH; fc < NFC; ++fc) {
            bf[fc][0] = *(const v8s*)(Bh + fc * 1024 + ak0);
            bf[fc][1] = *(const v8s*)(Bh + fc * 1024 + ak1);
        }
        if (tt + 1 < nt) stageA(bi ^ 1, 1);
        kA += 64;
        __builtin_amdgcn_s_barrier();
        asm volatile("s_waitcnt lgkmcnt(0)" ::: "memory");
        __builtin_amdgcn_s_setprio(1);
        #pragma unroll
        for (int fr = 0; fr < 4; ++fr)
            #pragma unroll
            for (int fc = FCH; fc < NFC; ++fc) {
                acc[fr][fc] = __builtin_amdgcn_mfma_f32_16x16x32_bf16(bf[fc][0], af[fr][0], acc[fr][fc], 0, 0, 0);
                acc[fr][fc] = __builtin_amdgcn_mfma_f32_16x16x32_bf16(bf[fc][1], af[fr][1], acc[fr][fc], 0, 0, 0);
            }
        __builtin_amdgcn_s_setprio(0);
        __builtin_amdgcn_s_barrier();

        #pragma unroll
        for (int fr = 0; fr < 4; ++fr) {
            af[fr][0] = *(const v8s*)(Ah + (fr + 4) * 1024 + ak0);
            af[fr][1] = *(const v8s*)(Ah + (fr + 4) * 1024 + ak1);
        }
        if (tt + 2 < nt) stageB(bi, 0);
        __builtin_amdgcn_s_barrier();
        asm volatile("s_waitcnt lgkmcnt(0)" ::: "memory");
        __builtin_amdgcn_s_setprio(1);
        #pragma unroll
        for (int fr = 0; fr < 4; ++fr)
            #pragma unroll
            for (int fc = 0; fc < FCH; ++fc) {
                acc[fr + 4][fc] = __builtin_amdgcn_mfma_f32_16x16x32_bf16(bf[fc][0], af[fr][0], acc[fr + 4][fc], 0, 0, 0);
                acc[fr + 4][fc] = __builtin_amdgcn_mfma_f32_16x16x32_bf16(bf[fc][1], af[fr][1], acc[fr + 4][fc], 0, 0, 0);
            }
        __builtin_amdgcn_s_setprio(0);
        __builtin_amdgcn_s_barrier();

        if (tt + 2 < nt) stageB(bi, 1);
        kB += 64;
        if (tt + 2 < nt)
            asm volatile("s_waitcnt vmcnt(%0)" :: "i"(2 * NLB) : "memory");
        else if (tt + 1 < nt)
            asm volatile("s_waitcnt vmcnt(0)" ::: "memory");
        __builtin_amdgcn_s_barrier();
        __builtin_amdgcn_s_setprio(1);
        #pragma unroll
        for (int fr = 0; fr < 4; ++fr)
            #pragma unroll
            for (int fc = FCH; fc < NFC; ++fc) {
                acc[fr + 4][fc] = __builtin_amdgcn_mfma_f32_16x16x32_bf16(bf[fc][0], af[fr][0], acc[fr + 4][fc], 0, 0, 0);
                acc[fr + 4][fc] = __builtin_amdgcn_mfma_f32_16x16x32_bf16(bf[fc][1], af[fr][1], acc[fr + 4][fc], 0, 0, 0);
            }
        __builtin_amdgcn_s_setprio(0);
        __builtin_amdgcn_s_barrier();
    }

    // epilogue: residual add, x write, per-row partial stats over this block's 128 cols
    float p1[8], p2[8];
    #pragma unroll
    for (int fr = 0; fr < 8; ++fr) { p1[fr] = 0.f; p2[fr] = 0.f; }
    #pragma unroll
    for (int fr = 0; fr < 8; ++fr) {
        long m = tileM + wmh * 128 + fr * 16 + l16;
        #pragma unroll
        for (int fc = 0; fc < NFC; ++fc) {
            long n0 = tileN + wn * (BN / 4) + fc * 16 + quad * 4;
            float4 bi4 = *(const float4*)&bias[n0];
            const float* bip = (const float*)&bi4;
            ushort4 xr4 = *(const ushort4*)&x[m * 512 + n0];
            const unsigned short* xp = (const unsigned short*)&xr4;
            unsigned short pk[4];
            #pragma unroll
            for (int r = 0; r < 4; ++r) {
                float v = acc[fr][fc][r] + bip[r] + bf2f(xp[r]);
                p1[fr] += v; p2[fr] += v * v;
                pk[r] = f2bf(v);
            }
            *(ushort4*)&x[m * 512 + n0] = *(ushort4*)pk;
        }
    }
    #pragma unroll
    for (int fr = 0; fr < 8; ++fr) {
        p1[fr] += __shfl_xor(p1[fr], 16); p1[fr] += __shfl_xor(p1[fr], 32);
        p2[fr] += __shfl_xor(p2[fr], 16); p2[fr] += __shfl_xor(p2[fr], 32);
    }
    float* red = (float*)&Ab[0][0][0];          // reuse LDS: [256][4] s1 then s2
    if (quad == 0) {
        #pragma unroll
        for (int fr = 0; fr < 8; ++fr) {
            int r = wmh * 128 + fr * 16 + l16;
            red[r * 4 + wn] = p1[fr];
            red[1024 + r * 4 + wn] = p2[fr];
        }
    }
    __syncthreads();
    if (t < 256) {
        int r = t;
        float s1 = red[r * 4] + red[r * 4 + 1] + red[r * 4 + 2] + red[r * 4 + 3];
        float s2 = red[1024 + r * 4] + red[1024 + r * 4 + 1] + red[1024 + r * 4 + 2] + red[1024 + r * 4 + 3];
        long m = tileM + r;
        rowpart[m * 8 + yb * 2]     = s1;
        rowpart[m * 8 + yb * 2 + 1] = s2;
    }
}

// ------- fused tanh + class GEMMs (all 3 groups) + in-block triplet scan -------
// TM=64, grid 256. Reads x once; u stays in LDS; writes part[b][seg=blk%32][6][64].
__global__ __launch_bounds__(256) void tanh_scan_kernel(
        const unsigned short* __restrict__ A,       // x final [16384][512]
        const unsigned short* __restrict__ WT,      // role-g-folded wabcT 3x[64][512]
        const unsigned short* __restrict__ cls,     // clsb 3x[64][64]
        const float* __restrict__ rowpart,          // rowpart2 [m][8]
        const float* __restrict__ c1a, const float* __restrict__ c2a,
        float* __restrict__ part) {                 // [8*32][6*64]
    __shared__ unsigned short As[64][40] __attribute__((aligned(16)));
    __shared__ unsigned short Bs[3][64][40] __attribute__((aligned(16)));
    __shared__ unsigned short P[3][64 * 72] __attribute__((aligned(16)));
    __shared__ unsigned short U[64][200] __attribute__((aligned(16)));
    const int t = threadIdx.x;
    const int lane = t & 63, w = t >> 6;
    const int quad = lane >> 4, l16 = lane & 15;
    const long tileM = (long)blockIdx.x * 64;
    const int arow = t >> 2, acol = (t & 3) * 8;
    const int m = w * 16 + l16;                     // this lane's output row (local)

    const unsigned short* gA = A + (tileM + arow) * 512 + acol;
    const unsigned short* gB[3];
    #pragma unroll
    for (int g = 0; g < 3; ++g) gB[g] = WT + g * 32768 + arow * 512 + acol;

    v4f acc[3][4] = {};
    uint4 a0, b0[3];
    a0 = *(const uint4*)gA; gA += 32;
    #pragma unroll
    for (int g = 0; g < 3; ++g) { b0[g] = *(const uint4*)gB[g]; gB[g] += 32; }
    *(uint4*)&As[arow][acol] = a0;
    #pragma unroll
    for (int g = 0; g < 3; ++g) *(uint4*)&Bs[g][arow][acol] = b0[g];

    for (int kk = 0; kk < 16; ++kk) {
        __syncthreads();
        const bool more = kk < 15;
        if (more) {
            a0 = *(const uint4*)gA; gA += 32;
            #pragma unroll
            for (int g = 0; g < 3; ++g) { b0[g] = *(const uint4*)gB[g]; gB[g] += 32; }
        }
        v8s af = *(const v8s*)&As[m][quad * 8];
        #pragma unroll
        for (int g = 0; g < 3; ++g)
            #pragma unroll
            for (int fc = 0; fc < 4; ++fc) {
                v8s bfr = *(const v8s*)&Bs[g][fc * 16 + l16][quad * 8];
                acc[g][fc] = __builtin_amdgcn_mfma_f32_16x16x32_bf16(bfr, af, acc[g][fc], 0, 0, 0);
            }
        __syncthreads();
        if (more) {
            *(uint4*)&As[arow][acol] = a0;
            #pragma unroll
            for (int g = 0; g < 3; ++g) *(uint4*)&Bs[g][arow][acol] = b0[g];
        }
    }

    // role-LN fold + tanh -> P  (stats shared per row m)
    {
        long gm = tileM + m;
        float4 q0 = *(const float4*)&rowpart[gm * 8];
        float4 q1 = *(const float4*)&rowpart[gm * 8 + 4];
        float s1 = q0.x + q0.z + q1.x + q1.z;
        float s2 = q0.y + q0.w + q1.y + q1.w;
        float mu = s1 * (1.0f / 512.0f);
        float rinv = 1.0f / sqrtf(s2 * (1.0f / 512.0f) - mu * mu + 1e-5f);
        float rmu = rinv * mu;
        #pragma unroll
        for (int g = 0; g < 3; ++g)
            #pragma unroll
            for (int fc = 0; fc < 4; ++fc) {
                int n0 = fc * 16 + quad * 4;
                float4 c14 = *(const float4*)&c1a[g * 64 + n0];
                float4 c24 = *(const float4*)&c2a[g * 64 + n0];
                const float* c1p = (const float*)&c14;
                const float* c2p = (const float*)&c24;
                unsigned short pk[4];
                #pragma unroll
                for (int r = 0; r < 4; ++r)
                    pk[r] = f2bf(fast_tanh(rinv * acc[g][fc][r] - rmu * c1p[r] + c2p[r]));
                *(ushort4*)&P[g][m * 72 + n0] = *(ushort4*)pk;
            }
    }
    __syncthreads();

    // class GEMMs: u[m][g*64+c] = sum_r P[g][m][r] * cls[g][c][r]
    #pragma unroll
    for (int g = 0; g < 3; ++g) {
        v4f acc2[4] = {};
        #pragma unroll
        for (int ks = 0; ks < 2; ++ks) {
            v8s paf = *(const v8s*)&P[g][m * 72 + ks * 32 + quad * 8];
            #pragma unroll
            for (int jc = 0; jc < 4; ++jc) {
                v8s cf = *(const v8s*)&cls[g * 4096 + (jc * 16 + l16) * 64 + ks * 32 + quad * 8];
                acc2[jc] = __builtin_amdgcn_mfma_f32_16x16x32_bf16(cf, paf, acc2[jc], 0, 0, 0);
            }
        }
        #pragma unroll
        for (int jc = 0; jc < 4; ++jc) {
            int c0 = jc * 16 + quad * 4;
            unsigned short pk[4];
            #pragma unroll
            for (int r = 0; r < 4; ++r) pk[r] = f2bf(acc2[jc][r]);
            *(ushort4*)&U[m][g * 64 + c0] = *(ushort4*)pk;
        }
    }
    __syncthreads();

    // in-block exact-triplet scan over this 64-row segment (excludes l==2047)
    if (t < 64) {
        int c = t;
        int nl = (((int)(tileM & (LSEQ - 1))) == LSEQ - 64) ? 63 : 64;
        float sA = 0.f, sB = 0.f, sC = 0.f, T = 0.f, M = 0.f, Uu = 0.f;
        for (int l = 0; l < nl; ++l) {
            float ua = bf2f(U[l][c]);
            float ub = bf2f(U[l][64 + c]);
            float uc = bf2f(U[l][128 + c]);
            Uu += uc * T;
            M += uc * sB;
            T += ub * sA;
            sA += ua; sB += ub; sC += uc;
        }
        int b = (int)(tileM >> 11);
        int seg = (int)(tileM >> 6) & 31;
        float* p = part + ((size_t)(b * 32 + seg)) * 384 + c;
        p[0] = sA; p[64] = sB; p[128] = sC; p[192] = T; p[256] = M; p[320] = Uu;
    }
}

// ------- merged: segment combine (32 segs) + final LN + Wq GEMV -------
__global__ __launch_bounds__(64) void combine_final_kernel(const float* __restrict__ part,
        const unsigned short* __restrict__ x,
        const float* __restrict__ qw, const float* __restrict__ qb,
        const float* __restrict__ Wq, const float* __restrict__ bq,
        float* __restrict__ out, float inv_denom) {
    int b = blockIdx.x;
    int c = threadIdx.x;
    const float* p = part + (size_t)b * 32 * 384 + c;
    float A = p[0], B = p[64], Tt = p[192], Mt = p[256], Ut = p[320];
    for (int seg = 1; seg < 32; ++seg) {
        const float* q2 = p + seg * 384;
        float a2 = q2[0], b2 = q2[64], c2 = q2[128], t2 = q2[192], m2 = q2[256], u2 = q2[320];
        float Un = Ut + u2 + c2 * Tt + A * m2;
        float Tn = Tt + t2 + A * b2;
        float Mn = Mt + m2 + B * c2;
        A += a2; B += b2;
        Ut = Un; Tt = Tn; Mt = Mn;
    }
    __shared__ float q[512];
    __shared__ float mv[2];
    const unsigned short* xr = x + ((size_t)b * LSEQ + (LSEQ - 1)) * 512;
    float s1 = 0.f, s2 = 0.f;
    for (int i = c; i < 512; i += 64) { float v = bf2f(xr[i]); q[i] = v; s1 += v; s2 += v * v; }
    #pragma unroll
    for (int o = 32; o > 0; o >>= 1) { s1 += __shfl_down(s1, o); s2 += __shfl_down(s2, o); }
    if (c == 0) {
        float m = s1 * (1.0f / 512.0f);
        float var = s2 * (1.0f / 512.0f) - m * m;
        mv[0] = m; mv[1] = 1.0f / sqrtf(var + 1e-5f);
    }
    __syncthreads();
    float m = mv[0], r = mv[1];
    for (int i = c; i < 512; i += 64) q[i] = (q[i] - m) * r * qw[i] + qb[i];
    __syncthreads();
    float acc = 0.f;
    for (int d = 0; d < 512; ++d) acc += q[d] * Wq[d * 64 + c];
    out[b * 64 + c] = Ut * inv_denom + acc + bq[c];
}

extern "C" void kernel_launch(void* const* d_in, const int* in_sizes, int n_in,
                              void* d_out, int out_size, void* d_ws, size_t ws_size,
                              hipStream_t stream) {
    const int*   token_ids   = (const int*)d_in[0];
    const float* tok_emb     = (const float*)d_in[1];
    const float* pos_emb     = (const float*)d_in[2];
    const float* stem_ln_w   = (const float*)d_in[3];
    const float* stem_ln_b   = (const float*)d_in[4];
    const float* stem_w1     = (const float*)d_in[5];
    const float* stem_b1     = (const float*)d_in[6];
    const float* stem_w2     = (const float*)d_in[7];
    const float* stem_b2     = (const float*)d_in[8];
    const float* role_ln_w   = (const float*)d_in[9];
    const float* role_ln_b   = (const float*)d_in[10];
    const float* Wa          = (const float*)d_in[11];
    const float* Wb          = (const float*)d_in[12];
    const float* Wc          = (const float*)d_in[13];
    const float* class_a     = (const float*)d_in[14];
    const float* class_b     = (const float*)d_in[15];
    const float* class_c     = (const float*)d_in[16];
    const float* query_ln_w  = (const float*)d_in[17];
    const float* query_ln_b  = (const float*)d_in[18];
    const float* Wq          = (const float*)d_in[19];
    const float* bq          = (const float*)d_in[20];
    float* out = (float*)d_out;

    char* wsb = (char*)d_ws;
    unsigned short* x    = (unsigned short*)(wsb);              // 16,777,216
    unsigned short* Hb   = (unsigned short*)(wsb + 16777216);   // 33,554,432
    float* part          = (float*)(wsb + 50331648);            // 393,216 (8*32*384*4)
    unsigned short* w1T  = (unsigned short*)(wsb + 51118080);   // 2,097,152 (g-folded)
    unsigned short* w2T  = (unsigned short*)(wsb + 53215232);   // 2,097,152
    unsigned short* wabcT= (unsigned short*)(wsb + 55312384);   // 196,608 (role-g-folded)
    unsigned short* clsb = (unsigned short*)(wsb + 55508992);   // 24,576
    float* rowstat0      = (float*)(wsb + 55533568);            // 131,072
    float* rowpart1      = (float*)(wsb + 55664640);            // 524,288
    float* rowpart2      = (float*)(wsb + 56188928);            // 524,288
    float* c1buf         = (float*)(wsb + 56713216);            // 8,192
    float* c2buf         = (float*)(wsb + 56721408);            // 8,192
    float* c1a           = (float*)(wsb + 56729600);            // 768
    float* c2a           = (float*)(wsb + 56730368);            // 768

    setup_kernel<<<6310, 256, 0, stream>>>(token_ids, tok_emb, pos_emb,
        stem_ln_w, stem_ln_b, role_ln_w, role_ln_b, stem_b1,
        x, rowstat0,
        stem_w1, stem_w2, Wa, Wb, Wc, class_a, class_b, class_c,
        w1T, w2T, wabcT, clsb, c1buf, c2buf, c1a, c2a);

    // layer 0
    gemm_w1<0><<<dim3(64, 4), 512, 0, stream>>>(
        x, w1T, c1buf, c2buf, rowstat0, Hb);
    gemm_w2<<<dim3(64, 4), 512, 0, stream>>>(
        Hb, w2T, stem_b2, x, rowpart1);
    // layer 1
    gemm_w1<1><<<dim3(64, 4), 512, 0, stream>>>(
        x, w1T + 524288, c1buf + 1024, c2buf + 1024, rowpart1, Hb);
    gemm_w2<<<dim3(64, 4), 512, 0, stream>>>(
        Hb, w2T + 524288, stem_b2 + 512, x, rowpart2);

    tanh_scan_kernel<<<256, 256, 0, stream>>>(x, wabcT, clsb,
                                              rowpart2, c1a, c2a, part);

    float inv_denom = (float)(6.0 / (2047.0 * 2046.0 * 2045.0));
    combine_final_kernel<<<NB, 64, 0, stream>>>(part, x, query_ln_w, query_ln_b,
                                                Wq, bq, out, inv_denom);
}

// Round 9
// 324.709 us; speedup vs baseline: 1.0834x; 1.0059x over previous
//
#include <hip/hip_runtime.h>

#define NROWS 16384   // B*L
#define LSEQ  2048
#define NB    8

typedef short v8s __attribute__((ext_vector_type(8)));
typedef float v4f __attribute__((ext_vector_type(4)));

__device__ __forceinline__ unsigned short f2bf(float f) {
    unsigned int u = __float_as_uint(f);
    return (unsigned short)((u + 0x7fffu + ((u >> 16) & 1u)) >> 16);
}
__device__ __forceinline__ float bf2f(unsigned short u) {
    return __uint_as_float(((unsigned int)u) << 16);
}

// async global->LDS, 16B per lane; LDS dest is wave-uniform base + lane*16
__device__ __forceinline__ void glds16(const void* g, void* l) {
    __builtin_amdgcn_global_load_lds(
        (__attribute__((address_space(1))) void*)g,
        (__attribute__((address_space(3))) void*)l,
        16, 0, 0);
}

// fast exact-GELU: Abramowitz-Stegun 5-term erf, |err|<1.5e-7
__device__ __forceinline__ float fast_gelu(float v) {
    float z = fabsf(v) * 0.70710678118654752f;
    float t = __builtin_amdgcn_rcpf(1.0f + 0.3275911f * z);
    float poly = t * (0.254829592f + t * (-0.284496736f + t * (1.421413741f +
                 t * (-1.453152027f + t * 1.061405429f))));
    float erfz = 1.0f - poly * __expf(-z * z);
    float er = copysignf(erfz, v);
    return 0.5f * v * (1.0f + er);
}
__device__ __forceinline__ float fast_tanh(float y) {
    float e = __expf(2.0f * y);
    return (e - 1.0f) * __builtin_amdgcn_rcpf(e + 1.0f);
}

// XCD row-swizzle for 256-row consumer tiles (BM=256 GEMMs): block b (of 2048,
// 8 rows each) -> rows of 256-row tile U with U%8 == b%8, so the embed
// producer's XCD matches gemm_w1<0>'s A-reader XCD (= (m>>8)%8).
__device__ __forceinline__ long swr256(int b, int r8) {
    int U = (b & 7) | (((b >> 3) & 7) << 3);    // 0..63, U%8 == b%8
    int chunk = b >> 6;                          // 0..31
    return (long)U * 256 + chunk * 8 + r8;
}

// ------- merged setup:
//   blocks 0..2047     : embed (XCD-swizzled, 8 rows/block = 2 rows/wave ILP)
//   blocks 2048..4191  : weight transposes; gamma FOLDED into w1T / wabcT
//   blocks 4192..4194  : class bf16 converts
//   blocks 4195..4258  : w1 LN colsum constants c1,c2 (64 blocks, k-split)
//   blocks 4259..4261  : wa/wb/wc LN colsum constants c1a,c2a (3 blocks, k-split)
__global__ __launch_bounds__(256) void setup_kernel(
        const int* __restrict__ ids,
        const float* __restrict__ tok, const float* __restrict__ pos,
        const float* __restrict__ g0, const float* __restrict__ b0,   // stem_ln_w/b [2][512]
        const float* __restrict__ rolew, const float* __restrict__ roleb,
        const float* __restrict__ b1all,                              // stem_b1 [2][1024]
        unsigned short* __restrict__ x, float* __restrict__ rowstat0,
        const float* __restrict__ w1, const float* __restrict__ w2,
        const float* __restrict__ wa, const float* __restrict__ wb, const float* __restrict__ wc,
        const float* __restrict__ ca, const float* __restrict__ cb, const float* __restrict__ cc,
        unsigned short* __restrict__ w1T, unsigned short* __restrict__ w2T,
        unsigned short* __restrict__ wabcT, unsigned short* __restrict__ clsb,
        float* __restrict__ c1buf, float* __restrict__ c2buf,
        float* __restrict__ c1a, float* __restrict__ c2a) {
    int blk = blockIdx.x;
    int t = threadIdx.x;
    if (blk < 2048) {
        int wave = t >> 6, lane = t & 63;
        int d = lane * 8;
        long row0 = swr256(blk, wave);
        long row1 = swr256(blk, wave + 4);
        int l0 = (int)(row0 & (LSEQ - 1)), l1 = (int)(row1 & (LSEQ - 1));
        int id0 = ids[row0], id1 = ids[row1];
        // issue all 8 gathers up front (2 rows in flight per wave)
        float4 ta0 = *(const float4*)(tok + (size_t)id0 * 512 + d);
        float4 ta1 = *(const float4*)(tok + (size_t)id0 * 512 + d + 4);
        float4 tb0 = *(const float4*)(tok + (size_t)id1 * 512 + d);
        float4 tb1 = *(const float4*)(tok + (size_t)id1 * 512 + d + 4);
        float4 pa0 = *(const float4*)(pos + (size_t)l0 * 512 + d);
        float4 pa1 = *(const float4*)(pos + (size_t)l0 * 512 + d + 4);
        float4 pb0 = *(const float4*)(pos + (size_t)l1 * 512 + d);
        float4 pb1 = *(const float4*)(pos + (size_t)l1 * 512 + d + 4);
        float a[8] = {ta0.x + pa0.x, ta0.y + pa0.y, ta0.z + pa0.z, ta0.w + pa0.w,
                      ta1.x + pa1.x, ta1.y + pa1.y, ta1.z + pa1.z, ta1.w + pa1.w};
        float b[8] = {tb0.x + pb0.x, tb0.y + pb0.y, tb0.z + pb0.z, tb0.w + pb0.w,
                      tb1.x + pb1.x, tb1.y + pb1.y, tb1.z + pb1.z, tb1.w + pb1.w};
        unsigned int xp[4], yp[4];
        #pragma unroll
        for (int i = 0; i < 4; ++i) {
            xp[i] = (unsigned int)f2bf(a[2 * i]) | ((unsigned int)f2bf(a[2 * i + 1]) << 16);
            yp[i] = (unsigned int)f2bf(b[2 * i]) | ((unsigned int)f2bf(b[2 * i + 1]) << 16);
        }
        *(uint4*)(x + row0 * 512 + d) = *(uint4*)xp;
        *(uint4*)(x + row1 * 512 + d) = *(uint4*)yp;
        float sa = 0.f, sa2 = 0.f, sb = 0.f, sb2 = 0.f;
        #pragma unroll
        for (int i = 0; i < 8; ++i) {
            sa += a[i]; sa2 += a[i] * a[i];
            sb += b[i]; sb2 += b[i] * b[i];
        }
        #pragma unroll
        for (int o = 32; o > 0; o >>= 1) {
            sa += __shfl_down(sa, o); sa2 += __shfl_down(sa2, o);
            sb += __shfl_down(sb, o); sb2 += __shfl_down(sb2, o);
        }
        if (lane == 0) {
            rowstat0[row0 * 2] = sa; rowstat0[row0 * 2 + 1] = sa2;
            rowstat0[row1 * 2] = sb; rowstat0[row1 * 2 + 1] = sb2;
        }
    } else if (blk < 4192) {
        int id = blk - 2048;
        int tx = t & 31, ty = t >> 5;
        const float* in; unsigned short* out; int R, C, bx, by, ldo;
        const float* gfold = nullptr;    // row-index (k) gamma fold
        if (id < 1024) {
            int l = id >> 9, r = id & 511;
            in = w1 + l * 524288; out = w1T + l * 524288;
            R = 512; C = 1024; bx = r & 31; by = r >> 5; ldo = 512;
            gfold = g0 + l * 512;
        } else if (id < 2048) {
            int l = (id - 1024) >> 9, r = (id - 1024) & 511;
            in = w2 + l * 524288; out = w2T + l * 524288;
            R = 1024; C = 512; bx = r & 15; by = r >> 4; ldo = 1024;
        } else {
            int g = (id - 2048) >> 5, r = (id - 2048) & 31;
            in = (g == 0) ? wa : (g == 1) ? wb : wc;
            out = wabcT + g * 32768;
            R = 512; C = 64; bx = r & 1; by = r >> 1; ldo = 512;
            gfold = rolew;
        }
        __shared__ unsigned short tile[32][33];
        int c0 = bx * 32, r0 = by * 32;
        for (int i = ty; i < 32; i += 8) {
            int r = r0 + i, c = c0 + tx;
            float v = (r < R && c < C) ? in[(size_t)r * C + c] : 0.f;
            if (gfold && r < R) v *= gfold[r];
            tile[i][tx] = f2bf(v);
        }
        __syncthreads();
        for (int i = ty; i < 32; i += 8) {
            int c = c0 + i, r = r0 + tx;
            if (r < R && c < C) out[(size_t)c * ldo + r] = tile[tx][i];
        }
    } else if (blk < 4195) {
        int g = blk - 4192;
        const float* src = (g == 0) ? ca : (g == 1) ? cb : cc;
        unsigned short* dst = clsb + g * 4096;
        for (int i = t; i < 4096; i += 256) dst[i] = f2bf(src[i]);
    } else if (blk < 4259) {
        // w1 colsums, parallel: 64 blocks = 2 layers x 32 n-chunks of 32.
        int idx = blk - 4195;
        int l = idx >> 5, nch = idx & 31;
        int n = nch * 32 + (t & 31);
        int kq = t >> 5;
        const float* W = w1 + l * 524288;
        const float* g = g0 + l * 512;
        const float* b = b0 + l * 512;
        float a1 = 0.f, a2 = 0.f;
        for (int k = kq * 64; k < kq * 64 + 64; ++k) {
            float w = W[(size_t)k * 1024 + n];
            a1 += g[k] * w;
            a2 += b[k] * w;
        }
        __shared__ float red1[8][32], red2[8][32];
        red1[kq][t & 31] = a1;
        red2[kq][t & 31] = a2;
        __syncthreads();
        if (t < 32) {
            float s1 = 0.f, s2 = 0.f;
            #pragma unroll
            for (int q = 0; q < 8; ++q) { s1 += red1[q][t]; s2 += red2[q][t]; }
            int nn = nch * 32 + t;
            c1buf[l * 1024 + nn] = s1;
            c2buf[l * 1024 + nn] = s2 + b1all[l * 1024 + nn];
        }
    } else {
        // abc colsums: 3 blocks, one per group; threads: n=t&63, kq=t>>6 (4x128)
        int gi = blk - 4259;
        const float* W = (gi == 0) ? wa : (gi == 1) ? wb : wc;
        int n = t & 63, kq = t >> 6;
        float a1 = 0.f, a2 = 0.f;
        for (int k = kq * 128; k < kq * 128 + 128; ++k) {
            float w = W[(size_t)k * 64 + n];
            a1 += rolew[k] * w;
            a2 += roleb[k] * w;
        }
        __shared__ float red1[4][64], red2[4][64];
        red1[kq][n] = a1;
        red2[kq][n] = a2;
        __syncthreads();
        if (t < 64) {
            float s1 = 0.f, s2 = 0.f;
            #pragma unroll
            for (int q = 0; q < 4; ++q) { s1 += red1[q][t]; s2 += red2[q][t]; }
            c1a[gi * 64 + t] = s1;
            c2a[gi * 64 + t] = s2;
        }
    }
}

// ------- w1 GEMM: 8-phase BM=256 BN=256, reads raw x, LN folded -------
// h = gelu( rinv*acc - rinv*mu*c1[n] + c2[n] )
// SM=0: stats = rowstat0[m][2] direct.  SM=1: stats = rowpart[m][4][2], sum 4.
template <int SM>
__global__ __launch_bounds__(512, 1) void gemm_w1(
        const unsigned short* __restrict__ A,      // x [16384][512]
        const unsigned short* __restrict__ BT,     // g-folded w1T [1024][512]
        const float* __restrict__ c1, const float* __restrict__ c2,
        const float* __restrict__ stats,
        unsigned short* __restrict__ Cout) {       // Hb [16384][1024]
    constexpr int BN = 256, NFC = 4, FCH = 2, NLB = 2, BH = 128;
    constexpr int lda = 512, ldb = 512, ldc = 1024, K = 512;
    __shared__ unsigned short Ab[2][2][128 * 64] __attribute__((aligned(16)));
    __shared__ unsigned short Bb[2][2][BH * 64] __attribute__((aligned(16)));
    const int t = threadIdx.x;
    const int lane = t & 63, w = t >> 6;
    const int quad = lane >> 4, l16 = lane & 15;
    const int wmh = w >> 2;
    const int wn  = w & 3;
    const int bhalf = wn >> 1, bbase = (wn & 1) * (BN / 4);
    const long tileM = (long)blockIdx.x * 256;
    const long tileN = (long)blockIdx.y * BN;

    const int rl = lane >> 3;
    const int cl = ((lane & 7) ^ rl) * 8;

    const unsigned short* pa[2][2];
    #pragma unroll
    for (int h = 0; h < 2; ++h)
        #pragma unroll
        for (int q = 0; q < 2; ++q)
            pa[h][q] = A + (tileM + h * 128 + w * 16 + q * 8 + rl) * (size_t)lda + cl;
    const unsigned short* pb[2][2];
    #pragma unroll
    for (int h = 0; h < 2; ++h)
        #pragma unroll
        for (int q = 0; q < 2; ++q)
            pb[h][q] = BT + (tileN + h * BH + w * 16 + q * 8 + rl) * (size_t)ldb + cl;
    int kA = 0, kB = 0;

    auto stageA = [&](int buf, int h) {
        glds16(pa[h][0] + kA, &Ab[buf][h][(w * 2 + 0) * 512]);
        glds16(pa[h][1] + kA, &Ab[buf][h][(w * 2 + 1) * 512]);
    };
    auto stageB = [&](int buf, int h) {
        glds16(pb[h][0] + kB, &Bb[buf][h][(w * 2 + 0) * 512]);
        glds16(pb[h][1] + kB, &Bb[buf][h][(w * 2 + 1) * 512]);
    };

    const int xl = l16 & 7;
    const int ak0 = l16 * 64 + (((quad    ) ^ xl) * 8);
    const int ak1 = l16 * 64 + (((quad + 4) ^ xl) * 8);

    stageA(0, 0); stageA(0, 1); kA = 64;
    stageB(0, 0); stageB(0, 1); kB = 64;
    stageB(1, 0); stageB(1, 1); kB = 128;

    v4f acc[8][NFC] = {};
    const int nt = K >> 6;

    asm volatile("s_waitcnt vmcnt(%0)" :: "i"(2 * NLB) : "memory");
    __builtin_amdgcn_s_barrier();

    for (int tt = 0; tt < nt; ++tt) {
        const int bi = tt & 1;
        const unsigned short* Ah = &Ab[bi][wmh][0];
        const unsigned short* Bh = &Bb[bi][bhalf][bbase * 64];
        v8s af[4][2], bf[NFC][2];

        #pragma unroll
        for (int fr = 0; fr < 4; ++fr) {
            af[fr][0] = *(const v8s*)(Ah + fr * 1024 + ak0);
            af[fr][1] = *(const v8s*)(Ah + fr * 1024 + ak1);
        }
        #pragma unroll
        for (int fc = 0; fc < FCH; ++fc) {
            bf[fc][0] = *(const v8s*)(Bh + fc * 1024 + ak0);
            bf[fc][1] = *(const v8s*)(Bh + fc * 1024 + ak1);
        }
        if (tt + 1 < nt) stageA(bi ^ 1, 0);
        __builtin_amdgcn_s_barrier();
        asm volatile("s_waitcnt lgkmcnt(0)" ::: "memory");
        __builtin_amdgcn_s_setprio(1);
        #pragma unroll
        for (int fr = 0; fr < 4; ++fr)
            #pragma unroll
            for (int fc = 0; fc < FCH; ++fc) {
                acc[fr][fc] = __builtin_amdgcn_mfma_f32_16x16x32_bf16(bf[fc][0], af[fr][0], acc[fr][fc], 0, 0, 0);
                acc[fr][fc] = __builtin_amdgcn_mfma_f32_16x16x32_bf16(bf[fc][1], af[fr][1], acc[fr][fc], 0, 0, 0);
            }
        __builtin_amdgcn_s_setprio(0);
        __builtin_amdgcn_s_barrier();

        #pragma unroll
        for (int fc = FCH; fc < NFC; ++fc) {
            bf[fc][0] = *(const v8s*)(Bh + fc * 1024 + ak0);
            bf[fc][1] = *(const v8s*)(Bh + fc * 1024 + ak1);
        }
        if (tt + 1 < nt) stageA(bi ^ 1, 1);
        kA += 64;
        __builtin_amdgcn_s_barrier();
        asm volatile("s_waitcnt lgkmcnt(0)" ::: "memory");
        __builtin_amdgcn_s_setprio(1);
        #pragma unroll
        for (int fr = 0; fr < 4; ++fr)
            #pragma unroll
            for (int fc = FCH; fc < NFC; ++fc) {
                acc[fr][fc] = __builtin_amdgcn_mfma_f32_16x16x32_bf16(bf[fc][0], af[fr][0], acc[fr][fc], 0, 0, 0);
                acc[fr][fc] = __builtin_amdgcn_mfma_f32_16x16x32_bf16(bf[fc][1], af[fr][1], acc[fr][fc], 0, 0, 0);
            }
        __builtin_amdgcn_s_setprio(0);
        __builtin_amdgcn_s_barrier();

        #pragma unroll
        for (int fr = 0; fr < 4; ++fr) {
            af[fr][0] = *(const v8s*)(Ah + (fr + 4) * 1024 + ak0);
            af[fr][1] = *(const v8s*)(Ah + (fr + 4) * 1024 + ak1);
        }
        if (tt + 2 < nt) stageB(bi, 0);
        __builtin_amdgcn_s_barrier();
        asm volatile("s_waitcnt lgkmcnt(0)" ::: "memory");
        __builtin_amdgcn_s_setprio(1);
        #pragma unroll
        for (int fr = 0; fr < 4; ++fr)
            #pragma unroll
            for (int fc = 0; fc < FCH; ++fc) {
                acc[fr + 4][fc] = __builtin_amdgcn_mfma_f32_16x16x32_bf16(bf[fc][0], af[fr][0], acc[fr + 4][fc], 0, 0, 0);
                acc[fr + 4][fc] = __builtin_amdgcn_mfma_f32_16x16x32_bf16(bf[fc][1], af[fr][1], acc[fr + 4][fc], 0, 0, 0);
            }
        __builtin_amdgcn_s_setprio(0);
        __builtin_amdgcn_s_barrier();

        if (tt + 2 < nt) stageB(bi, 1);
        kB += 64;
        if (tt + 2 < nt)
            asm volatile("s_waitcnt vmcnt(%0)" :: "i"(2 * NLB) : "memory");
        else if (tt + 1 < nt)
            asm volatile("s_waitcnt vmcnt(0)" ::: "memory");
        __builtin_amdgcn_s_barrier();
        __builtin_amdgcn_s_setprio(1);
        #pragma unroll
        for (int fr = 0; fr < 4; ++fr)
            #pragma unroll
            for (int fc = FCH; fc < NFC; ++fc) {
                acc[fr + 4][fc] = __builtin_amdgcn_mfma_f32_16x16x32_bf16(bf[fc][0], af[fr][0], acc[fr + 4][fc], 0, 0, 0);
                acc[fr + 4][fc] = __builtin_amdgcn_mfma_f32_16x16x32_bf16(bf[fc][1], af[fr][1], acc[fr + 4][fc], 0, 0, 0);
            }
        __builtin_amdgcn_s_setprio(0);
        __builtin_amdgcn_s_barrier();
    }

    // epilogue: LN-fold + GELU
    #pragma unroll
    for (int fr = 0; fr < 8; ++fr) {
        long m = tileM + wmh * 128 + fr * 16 + l16;
        float s1, s2;
        if (SM == 0) {
            float2 st = *(const float2*)&stats[m * 2];
            s1 = st.x; s2 = st.y;
        } else {
            float4 q0 = *(const float4*)&stats[m * 8];
            float4 q1 = *(const float4*)&stats[m * 8 + 4];
            s1 = q0.x + q0.z + q1.x + q1.z;
            s2 = q0.y + q0.w + q1.y + q1.w;
        }
        float mu = s1 * (1.0f / 512.0f);
        float rinv = 1.0f / sqrtf(s2 * (1.0f / 512.0f) - mu * mu + 1e-5f);
        float rmu = rinv * mu;
        #pragma unroll
        for (int fc = 0; fc < NFC; ++fc) {
            long n0 = tileN + wn * (BN / 4) + fc * 16 + quad * 4;
            float4 c14 = *(const float4*)&c1[n0];
            float4 c24 = *(const float4*)&c2[n0];
            const float* c1p = (const float*)&c14;
            const float* c2p = (const float*)&c24;
            unsigned short pk[4];
            #pragma unroll
            for (int r = 0; r < 4; ++r)
                pk[r] = f2bf(fast_gelu(rinv * acc[fr][fc][r] - rmu * c1p[r] + c2p[r]));
            *(ushort4*)&Cout[m * ldc + n0] = *(ushort4*)pk;
        }
    }
}

// ------- w2 GEMM: 8-phase BM=256 BN=128, residual + x write + row-stat partials -------
__global__ __launch_bounds__(512, 1) void gemm_w2(
        const unsigned short* __restrict__ A,      // Hb [16384][1024]
        const unsigned short* __restrict__ BT,     // w2T [512][1024]
        const float* __restrict__ bias,            // b2 [512]
        unsigned short* __restrict__ x,            // residual in/out [16384][512]
        float* __restrict__ rowpart) {             // [16384][4][2]
    constexpr int BN = 128, NFC = 2, FCH = 1, NLB = 1, BH = 64;
    constexpr int lda = 1024, ldb = 1024, K = 1024;
    __shared__ unsigned short Ab[2][2][128 * 64] __attribute__((aligned(16)));
    __shared__ unsigned short Bb[2][2][BH * 64] __attribute__((aligned(16)));
    const int t = threadIdx.x;
    const int lane = t & 63, w = t >> 6;
    const int quad = lane >> 4, l16 = lane & 15;
    const int wmh = w >> 2;
    const int wn  = w & 3;
    const int bhalf = wn >> 1, bbase = (wn & 1) * (BN / 4);
    const long tileM = (long)blockIdx.x * 256;
    const int yb = blockIdx.y;
    const long tileN = (long)yb * BN;

    const int rl = lane >> 3;
    const int cl = ((lane & 7) ^ rl) * 8;

    const unsigned short* pa[2][2];
    #pragma unroll
    for (int h = 0; h < 2; ++h)
        #pragma unroll
        for (int q = 0; q < 2; ++q)
            pa[h][q] = A + (tileM + h * 128 + w * 16 + q * 8 + rl) * (size_t)lda + cl;
    const unsigned short* pb[2];
    #pragma unroll
    for (int h = 0; h < 2; ++h)
        pb[h] = BT + (tileN + h * BH + w * 8 + rl) * (size_t)ldb + cl;
    int kA = 0, kB = 0;

    auto stageA = [&](int buf, int h) {
        glds16(pa[h][0] + kA, &Ab[buf][h][(w * 2 + 0) * 512]);
        glds16(pa[h][1] + kA, &Ab[buf][h][(w * 2 + 1) * 512]);
    };
    auto stageB = [&](int buf, int h) {
        glds16(pb[h] + kB, &Bb[buf][h][w * 512]);
    };

    const int xl = l16 & 7;
    const int ak0 = l16 * 64 + (((quad    ) ^ xl) * 8);
    const int ak1 = l16 * 64 + (((quad + 4) ^ xl) * 8);

    stageA(0, 0); stageA(0, 1); kA = 64;
    stageB(0, 0); stageB(0, 1); kB = 64;
    stageB(1, 0); stageB(1, 1); kB = 128;

    v4f acc[8][NFC] = {};
    const int nt = K >> 6;

    asm volatile("s_waitcnt vmcnt(%0)" :: "i"(2 * NLB) : "memory");
    __builtin_amdgcn_s_barrier();

    for (int tt = 0; tt < nt; ++tt) {
        const int bi = tt & 1;
        const unsigned short* Ah = &Ab[bi][wmh][0];
        const unsigned short* Bh = &Bb[bi][bhalf][bbase * 64];
        v8s af[4][2], bf[NFC][2];

        #pragma unroll
        for (int fr = 0; fr < 4; ++fr) {
            af[fr][0] = *(const v8s*)(Ah + fr * 1024 + ak0);
            af[fr][1] = *(const v8s*)(Ah + fr * 1024 + ak1);
        }
        #pragma unroll
        for (int fc = 0; fc < FCH; ++fc) {
            bf[fc][0] = *(const v8s*)(Bh + fc * 1024 + ak0);
            bf[fc][1] = *(const v8s*)(Bh + fc * 1024 + ak1);
        }
        if (tt + 1 < nt) stageA(bi ^ 1, 0);
        __builtin_amdgcn_s_barrier();
        asm volatile("s_waitcnt lgkmcnt(0)" ::: "memory");
        __builtin_amdgcn_s_setprio(1);
        #pragma unroll
        for (int fr = 0; fr < 4; ++fr)
            #pragma unroll
            for (int fc = 0; fc < FCH; ++fc) {
                acc[fr][fc] = __builtin_amdgcn_mfma_f32_16x16x32_bf16(bf[fc][0], af[fr][0], acc[fr][fc], 0, 0, 0);
                acc[fr][fc] = __builtin_amdgcn_mfma_f32_16x16x32_bf16(bf[fc][1], af[fr][1], acc[fr][fc], 0, 0, 0);
            }
        __builtin_amdgcn_s_setprio(0);
        __builtin_amdgcn_s_barrier();

        #pragma unroll
        for (int fc = FCH; fc < NFC; ++fc) {
            bf[fc][0] = *(const v8s*)(Bh + fc * 1024 + ak0);
            bf[fc][1] = *(const v8s*)(Bh + fc * 1024 + ak1);
        }
        if (tt + 1 < nt) stageA(bi ^ 1, 1);
        kA += 64;
        __builtin_amdgcn_s_barrier();
        asm volatile("s_waitcnt lgkmcnt(0)" ::: "memory");
        __builtin_amdgcn_s_setprio(1);
        #pragma unroll
        for (int fr = 0; fr < 4; ++fr)
            #pragma unroll
            for (int fc = FCH; fc < NFC; ++fc) {
                acc[fr][fc] = __builtin_amdgcn_mfma_f32_16x16x32_bf16(bf[fc][0], af[fr][0], acc[fr][fc], 0, 0, 0);
                acc[fr][fc] = __builtin_amdgcn_mfma_f32_16x16x32_bf16(bf[fc][1], af[fr][1], acc[fr][fc], 0, 0, 0);
            }
        __builtin_amdgcn_s_setprio(0);
        __builtin_amdgcn_s_barrier();

        #pragma unroll
        for (int fr = 0; fr < 4; ++fr) {
            af[fr][0] = *(const v8s*)(Ah + (fr + 4) * 1024 + ak0);
            af[fr][1] = *(const v8s*)(Ah + (fr + 4) * 1024 + ak1);
        }
        if (tt + 2 < nt) stageB(bi, 0);
        __builtin_amdgcn_s_barrier();
        asm volatile("s_waitcnt lgkmcnt(0)" ::: "memory");
        __builtin_amdgcn_s_setprio(1);
        #pragma unroll
        for (int fr = 0; fr < 4; ++fr)
            #pragma unroll
            for (int fc = 0; fc < FCH; ++fc) {
                acc[fr + 4][fc] = __builtin_amdgcn_mfma_f32_16x16x32_bf16(bf[fc][0], af[fr][0], acc[fr + 4][fc], 0, 0, 0);
                acc[fr + 4][fc] = __builtin_amdgcn_mfma_f32_16x16x32_bf16(bf[fc][1], af[fr][1], acc[fr + 4][fc], 0, 0, 0);
            }
        __builtin_amdgcn_s_setprio(0);
        __builtin_amdgcn_s_barrier();

        if (tt + 2 < nt) stageB(bi, 1);
        kB += 64;
        if (tt + 2 < nt)
            asm volatile("s_waitcnt vmcnt(%0)" :: "i"(2 * NLB) : "memory");
        else if (tt + 1 < nt)
            asm volatile("s_waitcnt vmcnt(0)" ::: "memory");
        __builtin_amdgcn_s_barrier();
        __builtin_amdgcn_s_setprio(1);
        #pragma unroll
        for (int fr = 0; fr < 4; ++fr)
            #pragma unroll
            for (int fc = FCH; fc < NFC; ++fc) {
                acc[fr + 4][fc] = __builtin_amdgcn_mfma_f32_16x16x32_bf16(bf[fc][0], af[fr][0], acc[fr + 4][fc], 0, 0, 0);
                acc[fr + 4][fc] = __builtin_amdgcn_mfma_f32_16x16x32_bf16(bf[fc][1], af[fr][1], acc[fr + 4][fc], 0, 0, 0);
            }
        __builtin_amdgcn_s_setprio(0);
        __builtin_amdgcn_s_barrier();
    }

    // epilogue: residual add, x write, per-row partial stats over this block's 128 cols
    float p1[8], p2[8];
    #pragma unroll
    for (int fr = 0; fr < 8; ++fr) { p1[fr] = 0.f; p2[fr] = 0.f; }
    #pragma unroll
    for (int fr = 0; fr < 8; ++fr) {
        long m = tileM + wmh * 128 + fr * 16 + l16;
        #pragma unroll
        for (int fc = 0; fc < NFC; ++fc) {
            long n0 = tileN + wn * (BN / 4) + fc * 16 + quad * 4;
            float4 bi4 = *(const float4*)&bias[n0];
            const float* bip = (const float*)&bi4;
            ushort4 xr4 = *(const ushort4*)&x[m * 512 + n0];
            const unsigned short* xp = (const unsigned short*)&xr4;
            unsigned short pk[4];
            #pragma unroll
            for (int r = 0; r < 4; ++r) {
                float v = acc[fr][fc][r] + bip[r] + bf2f(xp[r]);
                p1[fr] += v; p2[fr] += v * v;
                pk[r] = f2bf(v);
            }
            *(ushort4*)&x[m * 512 + n0] = *(ushort4*)pk;
        }
    }
    #pragma unroll
    for (int fr = 0; fr < 8; ++fr) {
        p1[fr] += __shfl_xor(p1[fr], 16); p1[fr] += __shfl_xor(p1[fr], 32);
        p2[fr] += __shfl_xor(p2[fr], 16); p2[fr] += __shfl_xor(p2[fr], 32);
    }
    float* red = (float*)&Ab[0][0][0];          // reuse LDS: [256][4] s1 then s2
    if (quad == 0) {
        #pragma unroll
        for (int fr = 0; fr < 8; ++fr) {
            int r = wmh * 128 + fr * 16 + l16;
            red[r * 4 + wn] = p1[fr];
            red[1024 + r * 4 + wn] = p2[fr];
        }
    }
    __syncthreads();
    if (t < 256) {
        int r = t;
        float s1 = red[r * 4] + red[r * 4 + 1] + red[r * 4 + 2] + red[r * 4 + 3];
        float s2 = red[1024 + r * 4] + red[1024 + r * 4 + 1] + red[1024 + r * 4 + 2] + red[1024 + r * 4 + 3];
        long m = tileM + r;
        rowpart[m * 8 + yb * 2]     = s1;
        rowpart[m * 8 + yb * 2 + 1] = s2;
    }
}

// ------- fused tanh + class GEMMs (all 3 groups) + in-block triplet scan -------
// TM=64, grid 256, XCD-aligned tile mapping: tile T has (T>>2)%8 == blockIdx%8,
// so x rows are read on the same XCD whose w2 block wrote them.
__global__ __launch_bounds__(256) void tanh_scan_kernel(
        const unsigned short* __restrict__ A,       // x final [16384][512]
        const unsigned short* __restrict__ WT,      // role-g-folded wabcT 3x[64][512]
        const unsigned short* __restrict__ cls,     // clsb 3x[64][64]
        const float* __restrict__ rowpart,          // rowpart2 [m][8]
        const float* __restrict__ c1a, const float* __restrict__ c2a,
        float* __restrict__ part) {                 // [8*32][6*64]
    __shared__ unsigned short As[64][40] __attribute__((aligned(16)));
    __shared__ unsigned short Bs[3][64][40] __attribute__((aligned(16)));
    __shared__ unsigned short P[3][64 * 72] __attribute__((aligned(16)));
    __shared__ unsigned short U[64][200] __attribute__((aligned(16)));
    const int t = threadIdx.x;
    const int lane = t & 63, w = t >> 6;
    const int quad = lane >> 4, l16 = lane & 15;
    // bijective bit-permutation: i[2:0]->T[4:2], i[4:3]->T[1:0], i[7:5]->T[7:5]
    const int bi = blockIdx.x;
    const int T = ((bi & 7) << 2) | ((bi >> 3) & 3) | (bi & 0xE0);
    const long tileM = (long)T * 64;
    const int arow = t >> 2, acol = (t & 3) * 8;
    const int m = w * 16 + l16;                     // this lane's output row (local)

    const unsigned short* gA = A + (tileM + arow) * 512 + acol;
    const unsigned short* gB[3];
    #pragma unroll
    for (int g = 0; g < 3; ++g) gB[g] = WT + g * 32768 + arow * 512 + acol;

    v4f acc[3][4] = {};
    uint4 a0, b0[3];
    a0 = *(const uint4*)gA; gA += 32;
    #pragma unroll
    for (int g = 0; g < 3; ++g) { b0[g] = *(const uint4*)gB[g]; gB[g] += 32; }
    *(uint4*)&As[arow][acol] = a0;
    #pragma unroll
    for (int g = 0; g < 3; ++g) *(uint4*)&Bs[g][arow][acol] = b0[g];

    for (int kk = 0; kk < 16; ++kk) {
        __syncthreads();
        const bool more = kk < 15;
        if (more) {
            a0 = *(const uint4*)gA; gA += 32;
            #pragma unroll
            for (int g = 0; g < 3; ++g) { b0[g] = *(const uint4*)gB[g]; gB[g] += 32; }
        }
        v8s af = *(const v8s*)&As[m][quad * 8];
        #pragma unroll
        for (int g = 0; g < 3; ++g)
            #pragma unroll
            for (int fc = 0; fc < 4; ++fc) {
                v8s bfr = *(const v8s*)&Bs[g][fc * 16 + l16][quad * 8];
                acc[g][fc] = __builtin_amdgcn_mfma_f32_16x16x32_bf16(bfr, af, acc[g][fc], 0, 0, 0);
            }
        __syncthreads();
        if (more) {
            *(uint4*)&As[arow][acol] = a0;
            #pragma unroll
            for (int g = 0; g < 3; ++g) *(uint4*)&Bs[g][arow][acol] = b0[g];
        }
    }

    // role-LN fold + tanh -> P  (stats shared per row m)
    {
        long gm = tileM + m;
        float4 q0 = *(const float4*)&rowpart[gm * 8];
        float4 q1 = *(const float4*)&rowpart[gm * 8 + 4];
        float s1 = q0.x + q0.z + q1.x + q1.z;
        float s2 = q0.y + q0.w + q1.y + q1.w;
        float mu = s1 * (1.0f / 512.0f);
        float rinv = 1.0f / sqrtf(s2 * (1.0f / 512.0f) - mu * mu + 1e-5f);
        float rmu = rinv * mu;
        #pragma unroll
        for (int g = 0; g < 3; ++g)
            #pragma unroll
            for (int fc = 0; fc < 4; ++fc) {
                int n0 = fc * 16 + quad * 4;
                float4 c14 = *(const float4*)&c1a[g * 64 + n0];
                float4 c24 = *(const float4*)&c2a[g * 64 + n0];
                const float* c1p = (const float*)&c14;
                const float* c2p = (const float*)&c24;
                unsigned short pk[4];
                #pragma unroll
                for (int r = 0; r < 4; ++r)
                    pk[r] = f2bf(fast_tanh(rinv * acc[g][fc][r] - rmu * c1p[r] + c2p[r]));
                *(ushort4*)&P[g][m * 72 + n0] = *(ushort4*)pk;
            }
    }
    __syncthreads();

    // class GEMMs: u[m][g*64+c] = sum_r P[g][m][r] * cls[g][c][r]
    #pragma unroll
    for (int g = 0; g < 3; ++g) {
        v4f acc2[4] = {};
        #pragma unroll
        for (int ks = 0; ks < 2; ++ks) {
            v8s paf = *(const v8s*)&P[g][m * 72 + ks * 32 + quad * 8];
            #pragma unroll
            for (int jc = 0; jc < 4; ++jc) {
                v8s cf = *(const v8s*)&cls[g * 4096 + (jc * 16 + l16) * 64 + ks * 32 + quad * 8];
                acc2[jc] = __builtin_amdgcn_mfma_f32_16x16x32_bf16(cf, paf, acc2[jc], 0, 0, 0);
            }
        }
        #pragma unroll
        for (int jc = 0; jc < 4; ++jc) {
            int c0 = jc * 16 + quad * 4;
            unsigned short pk[4];
            #pragma unroll
            for (int r = 0; r < 4; ++r) pk[r] = f2bf(acc2[jc][r]);
            *(ushort4*)&U[m][g * 64 + c0] = *(ushort4*)pk;
        }
    }
    __syncthreads();

    // in-block exact-triplet scan over this 64-row segment (excludes l==2047)
    if (t < 64) {
        int c = t;
        int nl = (((int)(tileM & (LSEQ - 1))) == LSEQ - 64) ? 63 : 64;
        float sA = 0.f, sB = 0.f, sC = 0.f, Tt = 0.f, M = 0.f, Uu = 0.f;
        for (int l = 0; l < nl; ++l) {
            float ua = bf2f(U[l][c]);
            float ub = bf2f(U[l][64 + c]);
            float uc = bf2f(U[l][128 + c]);
            Uu += uc * Tt;
            M += uc * sB;
            Tt += ub * sA;
            sA += ua; sB += ub; sC += uc;
        }
        int b = (int)(tileM >> 11);
        int seg = (int)(tileM >> 6) & 31;
        float* p = part + ((size_t)(b * 32 + seg)) * 384 + c;
        p[0] = sA; p[64] = sB; p[128] = sC; p[192] = Tt; p[256] = M; p[320] = Uu;
    }
}

// ------- merged: segment combine (32 segs) + final LN + Wq GEMV -------
__global__ __launch_bounds__(64) void combine_final_kernel(const float* __restrict__ part,
        const unsigned short* __restrict__ x,
        const float* __restrict__ qw, const float* __restrict__ qb,
        const float* __restrict__ Wq, const float* __restrict__ bq,
        float* __restrict__ out, float inv_denom) {
    int b = blockIdx.x;
    int c = threadIdx.x;
    const float* p = part + (size_t)b * 32 * 384 + c;
    float A = p[0], B = p[64], Tt = p[192], Mt = p[256], Ut = p[320];
    for (int seg = 1; seg < 32; ++seg) {
        const float* q2 = p + seg * 384;
        float a2 = q2[0], b2 = q2[64], c2 = q2[128], t2 = q2[192], m2 = q2[256], u2 = q2[320];
        float Un = Ut + u2 + c2 * Tt + A * m2;
        float Tn = Tt + t2 + A * b2;
        float Mn = Mt + m2 + B * c2;
        A += a2; B += b2;
        Ut = Un; Tt = Tn; Mt = Mn;
    }
    __shared__ float q[512];
    __shared__ float mv[2];
    const unsigned short* xr = x + ((size_t)b * LSEQ + (LSEQ - 1)) * 512;
    float s1 = 0.f, s2 = 0.f;
    for (int i = c; i < 512; i += 64) { float v = bf2f(xr[i]); q[i] = v; s1 += v; s2 += v * v; }
    #pragma unroll
    for (int o = 32; o > 0; o >>= 1) { s1 += __shfl_down(s1, o); s2 += __shfl_down(s2, o); }
    if (c == 0) {
        float m = s1 * (1.0f / 512.0f);
        float var = s2 * (1.0f / 512.0f) - m * m;
        mv[0] = m; mv[1] = 1.0f / sqrtf(var + 1e-5f);
    }
    __syncthreads();
    float m = mv[0], r = mv[1];
    for (int i = c; i < 512; i += 64) q[i] = (q[i] - m) * r * qw[i] + qb[i];
    __syncthreads();
    float acc = 0.f;
    for (int d = 0; d < 512; ++d) acc += q[d] * Wq[d * 64 + c];
    out[b * 64 + c] = Ut * inv_denom + acc + bq[c];
}

extern "C" void kernel_launch(void* const* d_in, const int* in_sizes, int n_in,
                              void* d_out, int out_size, void* d_ws, size_t ws_size,
                              hipStream_t stream) {
    const int*   token_ids   = (const int*)d_in[0];
    const float* tok_emb     = (const float*)d_in[1];
    const float* pos_emb     = (const float*)d_in[2];
    const float* stem_ln_w   = (const float*)d_in[3];
    const float* stem_ln_b   = (const float*)d_in[4];
    const float* stem_w1     = (const float*)d_in[5];
    const float* stem_b1     = (const float*)d_in[6];
    const float* stem_w2     = (const float*)d_in[7];
    const float* stem_b2     = (const float*)d_in[8];
    const float* role_ln_w   = (const float*)d_in[9];
    const float* role_ln_b   = (const float*)d_in[10];
    const float* Wa          = (const float*)d_in[11];
    const float* Wb          = (const float*)d_in[12];
    const float* Wc          = (const float*)d_in[13];
    const float* class_a     = (const float*)d_in[14];
    const float* class_b     = (const float*)d_in[15];
    const float* class_c     = (const float*)d_in[16];
    const float* query_ln_w  = (const float*)d_in[17];
    const float* query_ln_b  = (const float*)d_in[18];
    const float* Wq          = (const float*)d_in[19];
    const float* bq          = (const float*)d_in[20];
    float* out = (float*)d_out;

    char* wsb = (char*)d_ws;
    unsigned short* x    = (unsigned short*)(wsb);              // 16,777,216
    unsigned short* Hb   = (unsigned short*)(wsb + 16777216);   // 33,554,432
    float* part          = (float*)(wsb + 50331648);            // 393,216 (8*32*384*4)
    unsigned short* w1T  = (unsigned short*)(wsb + 51118080);   // 2,097,152 (g-folded)
    unsigned short* w2T  = (unsigned short*)(wsb + 53215232);   // 2,097,152
    unsigned short* wabcT= (unsigned short*)(wsb + 55312384);   // 196,608 (role-g-folded)
    unsigned short* clsb = (unsigned short*)(wsb + 55508992);   // 24,576
    float* rowstat0      = (float*)(wsb + 55533568);            // 131,072
    float* rowpart1      = (float*)(wsb + 55664640);            // 524,288
    float* rowpart2      = (float*)(wsb + 56188928);            // 524,288
    float* c1buf         = (float*)(wsb + 56713216);            // 8,192
    float* c2buf         = (float*)(wsb + 56721408);            // 8,192
    float* c1a           = (float*)(wsb + 56729600);            // 768
    float* c2a           = (float*)(wsb + 56730368);            // 768

    setup_kernel<<<4262, 256, 0, stream>>>(token_ids, tok_emb, pos_emb,
        stem_ln_w, stem_ln_b, role_ln_w, role_ln_b, stem_b1,
        x, rowstat0,
        stem_w1, stem_w2, Wa, Wb, Wc, class_a, class_b, class_c,
        w1T, w2T, wabcT, clsb, c1buf, c2buf, c1a, c2a);

    // layer 0
    gemm_w1<0><<<dim3(64, 4), 512, 0, stream>>>(
        x, w1T, c1buf, c2buf, rowstat0, Hb);
    gemm_w2<<<dim3(64, 4), 512, 0, stream>>>(
        Hb, w2T, stem_b2, x, rowpart1);
    // layer 1
    gemm_w1<1><<<dim3(64, 4), 512, 0, stream>>>(
        x, w1T + 524288, c1buf + 1024, c2buf + 1024, rowpart1, Hb);
    gemm_w2<<<dim3(64, 4), 512, 0, stream>>>(
        Hb, w2T + 524288, stem_b2 + 512, x, rowpart2);

    tanh_scan_kernel<<<256, 256, 0, stream>>>(x, wabcT, clsb,
                                              rowpart2, c1a, c2a, part);

    float inv_denom = (float)(6.0 / (2047.0 * 2046.0 * 2045.0));
    combine_final_kernel<<<NB, 64, 0, stream>>>(part, x, query_ln_w, query_ln_b,
                                                Wq, bq, out, inv_denom);
}